// Round 17
// baseline (426.674 us; speedup 1.0000x reference)
//
#include <hip/hip_runtime.h>
#include <math.h>

#define NN 50000
#define EE 640000
#define HD 128
#define ECD 64
#define NHD 4
#define HH 32
#define SCAN_B 256
#define NBLK ((NN + SCAN_B - 1) / SCAN_B)   // 196
#define USTR 17   // LDS row stride in uints (32 bf16 = 16 uints + 1 pad)
#define NTILE (NN / 16)                     // 3125 (exact)

typedef short bf16x8 __attribute__((ext_vector_type(8)));
typedef float f32x4 __attribute__((ext_vector_type(4)));

__device__ __forceinline__ float ssp_f(float v) {
    return fmaxf(v, 0.0f) + __logf(1.0f + __expf(-fabsf(v))) - 0.69314718055994531f;
}
__device__ __forceinline__ unsigned f2bf_u(float f) {
    unsigned u = __float_as_uint(f);
    unsigned r = ((u >> 16) & 1u) + 0x7FFFu;
    return (u + r) >> 16;
}
__device__ __forceinline__ unsigned pk2(float a, float b) {
    return f2bf_u(a) | (f2bf_u(b) << 16);
}
__device__ __forceinline__ unsigned f2bf_f(float f) {
    return (__float_as_uint(f) + 0x8000u) >> 16;
}
__device__ __forceinline__ unsigned pk2f(float a, float b) {
    return f2bf_f(a) | (f2bf_f(b) << 16);
}
__device__ __forceinline__ void unp2(unsigned u, float& a, float& b) {
    a = __uint_as_float(u << 16);
    b = __uint_as_float(u & 0xffff0000u);
}
__device__ __forceinline__ bf16x8 as_bf(uint4 u) {
    union { uint4 a; bf16x8 b; } c; c.a = u; return c.b;
}

// ---------------- projection weight packer ----------------
__global__ __launch_bounds__(256) void k_pwfrag(
    const float* __restrict__ kw, const float* __restrict__ vw,
    const float* __restrict__ qw, const float* __restrict__ wklw,
    const float* __restrict__ wklb,
    uint4* __restrict__ pf, float* __restrict__ cw)
{
    const int t = threadIdx.x;
    #pragma unroll
    for (int it = 0; it < 6; ++it) {
        const int f = t + it * 256;      // 0..1535
        const int tg = f >> 9;
        const int rem = f & 511;
        const int nt = rem >> 6, l = rem & 63;
        const int lm = l & 15, lg = l >> 4;
        const int h = nt >> 1, od = (nt & 1) * 16 + lm;
        float val[8];
        if (tg == 2) {
            #pragma unroll
            for (int j = 0; j < 8; ++j) {
                float s = 0.f;
                for (int j2 = 0; j2 < 32; ++j2)
                    s += qw[(size_t)(h * 32 + j2) * 32 + lg * 8 + j] * wklw[j2 * 32 + od];
                val[j] = s;
            }
        } else {
            const float* wp = (tg == 0) ? kw : vw;
            #pragma unroll
            for (int j = 0; j < 8; ++j)
                val[j] = wp[(size_t)(h * 32 + od) * 32 + lg * 8 + j];
        }
        uint4 o;
        o.x = pk2(val[0], val[1]); o.y = pk2(val[2], val[3]);
        o.z = pk2(val[4], val[5]); o.w = pk2(val[6], val[7]);
        pf[f] = o;
    }
    #pragma unroll
    for (int d2 = 0; d2 < 2; ++d2) {
        const int idx = t * 2 + d2;     // 0..511
        const int h = idx >> 5, d = idx & 31;
        float s = 0.f;
        for (int j = 0; j < 32; ++j)
            s += qw[(size_t)(h * 32 + j) * 32 + d] * wklb[j];
        cw[idx] = s;
    }
}

// ---------------- K1: fused LN1 + c0 + MFMA projections ---------------------
__global__ __launch_bounds__(256) void k_ln1proj(
    const float* __restrict__ x, const float* __restrict__ ln1_g,
    const float* __restrict__ ln1_b, const float* __restrict__ cw,
    const uint4* __restrict__ pf, float* __restrict__ c0_out,
    unsigned short* __restrict__ hk16, unsigned short* __restrict__ hv16,
    unsigned short* __restrict__ g16)
{
    __shared__ unsigned ylds[16][68];   // 16 nodes x 64 uints, stride 68
    const int w = threadIdx.x >> 6, l = threadIdx.x & 63;
    const int lm = l & 15, lg = l >> 4;
    const int t0 = 2 * l;
    const float2 lg2 = *(const float2*)(ln1_g + t0);
    const float2 lb2 = *(const float2*)(ln1_b + t0);
    const float2 cw2 = *(const float2*)(cw + t0);

    for (int tile = blockIdx.x; tile < NTILE; tile += 1024) {
        const int n0 = tile * 16;
        __syncthreads();   // previous iteration's readers done
        #pragma unroll
        for (int it = 0; it < 4; ++it) {
            const int n = n0 + w * 4 + it;
            const float2 xv = *(const float2*)(x + (size_t)n * HD + t0);
            float s1 = xv.x + xv.y;
            float s2 = xv.x * xv.x + xv.y * xv.y;
            #pragma unroll
            for (int off = 1; off < 64; off <<= 1) {
                s1 += __shfl_xor(s1, off);
                s2 += __shfl_xor(s2, off);
            }
            const float mean = s1 * (1.0f / HD);
            const float var  = s2 * (1.0f / HD) - mean * mean;
            const float rstd = rsqrtf(var + 1e-5f);
            const float y0 = (xv.x - mean) * rstd * lg2.x + lb2.x;
            const float y1 = (xv.y - mean) * rstd * lg2.y + lb2.y;
            ylds[w * 4 + it][l] = pk2(y0, y1);
            float p = y0 * cw2.x + y1 * cw2.y;
            #pragma unroll
            for (int off = 1; off < 16; off <<= 1) p += __shfl_xor(p, off);
            if ((l & 15) == 0) c0_out[n * NHD + (l >> 4)] = p;
        }
        __syncthreads();
        // wave w's A fragment: head w, rows=nodes lm, k-slots lg*8..+7
        uint4 am;
        am.x = ylds[lm][w * 16 + lg * 4 + 0];
        am.y = ylds[lm][w * 16 + lg * 4 + 1];
        am.z = ylds[lm][w * 16 + lg * 4 + 2];
        am.w = ylds[lm][w * 16 + lg * 4 + 3];
        #pragma unroll
        for (int tg = 0; tg < 3; ++tg) {
            unsigned short* o = (tg == 0) ? hk16 : (tg == 1) ? hv16 : g16;
            #pragma unroll
            for (int q = 0; q < 2; ++q) {
                const int nt = 2 * w + q;
                f32x4 acc = f32x4{0.f, 0.f, 0.f, 0.f};
                acc = __builtin_amdgcn_mfma_f32_16x16x32_bf16(
                    as_bf(am), as_bf(pf[tg * 512 + nt * 64 + l]), acc, 0, 0, 0);
                #pragma unroll
                for (int r = 0; r < 4; ++r)
                    o[(size_t)(n0 + lg * 4 + r) * HD + nt * 16 + lm] =
                        (unsigned short)f2bf_u(acc[r]);
            }
        }
    }
}

// ---------------- CSR build ----------------
__global__ __launch_bounds__(256) void k_deg(
    const int* __restrict__ edge_index, int* __restrict__ deg)
{
    for (int e = blockIdx.x * blockDim.x + threadIdx.x; e < EE;
         e += gridDim.x * blockDim.x)
        atomicAdd(&deg[edge_index[e]], 1);
}

__global__ __launch_bounds__(SCAN_B) void k_scan_block(
    const int* __restrict__ deg, int* __restrict__ base, int* __restrict__ bsum)
{
    const int i = blockIdx.x * SCAN_B + threadIdx.x;
    const int v = (i < NN) ? deg[i] : 0;
    __shared__ int s[SCAN_B];
    s[threadIdx.x] = v;
    __syncthreads();
    for (int off = 1; off < SCAN_B; off <<= 1) {
        int t = (threadIdx.x >= off) ? s[threadIdx.x - off] : 0;
        __syncthreads();
        s[threadIdx.x] += t;
        __syncthreads();
    }
    if (i < NN) base[i] = s[threadIdx.x] - v;
    if (threadIdx.x == SCAN_B - 1) bsum[blockIdx.x] = s[SCAN_B - 1];
}

__global__ __launch_bounds__(SCAN_B) void k_scan_top(int* __restrict__ bsum)
{
    const int i = threadIdx.x;
    const int v = (i < NBLK) ? bsum[i] : 0;
    __shared__ int s[SCAN_B];
    s[i] = v;
    __syncthreads();
    for (int off = 1; off < SCAN_B; off <<= 1) {
        int t = (i >= off) ? s[i - off] : 0;
        __syncthreads();
        s[i] += t;
        __syncthreads();
    }
    if (i < NBLK) bsum[i] = s[i] - v;
}

__global__ __launch_bounds__(SCAN_B) void k_scan_add(
    int* __restrict__ base, const int* __restrict__ bsum, int* __restrict__ cursor)
{
    const int i = blockIdx.x * SCAN_B + threadIdx.x;
    if (i < NN) {
        const int b = base[i] + bsum[i >> 8];
        base[i] = b;
        cursor[i] = b;
    }
}

__global__ __launch_bounds__(256) void k_scatter(
    const int* __restrict__ edge_index, int* __restrict__ cursor,
    int* __restrict__ eidx, int* __restrict__ rowv, int* __restrict__ colv)
{
    for (int e = blockIdx.x * blockDim.x + threadIdx.x; e < EE;
         e += gridDim.x * blockDim.x) {
        const int r = edge_index[e];
        const int pos = atomicAdd(&cursor[r], 1);
        eidx[pos] = e;
        rowv[pos] = r;
        colv[pos] = edge_index[EE + e];
    }
}

// ---------------- edge-MLP weight fragment packer (1 block) ----------------
__global__ __launch_bounds__(256) void k_wfrag(
    const float* __restrict__ wk1_w, const float* __restrict__ wk2_w,
    const float* __restrict__ wv1_w, const float* __restrict__ wv2_w,
    uint4* __restrict__ frag)
{
    const int t = threadIdx.x;
    const int l = t & 63;
    const int lm = l & 15, lg = l >> 4;
    {
        const int f = t >> 6;          // 0..3
        const int kt = f >> 1, nt = f & 1;
        const int out = nt * 16 + lm;
        uint4 a, b;
        unsigned ra[4], rb[4];
        #pragma unroll
        for (int p = 0; p < 4; ++p) {
            const int in0 = kt * 32 + lg * 8 + 2 * p;
            ra[p] = pk2(wk1_w[(size_t)out * ECD + in0], wk1_w[(size_t)out * ECD + in0 + 1]);
            rb[p] = pk2(wv1_w[(size_t)out * ECD + in0], wv1_w[(size_t)out * ECD + in0 + 1]);
        }
        a.x = ra[0]; a.y = ra[1]; a.z = ra[2]; a.w = ra[3];
        b.x = rb[0]; b.y = rb[1]; b.z = rb[2]; b.w = rb[3];
        frag[f * 64 + l] = a;
        frag[(6 + f) * 64 + l] = b;
    }
    if (t < 128) {
        const int nt = t >> 6;
        const int out = nt * 16 + lm;
        uint4 a, b;
        unsigned ra[4], rb[4];
        #pragma unroll
        for (int p = 0; p < 4; ++p) {
            const int in0 = lg * 8 + 2 * p;
            ra[p] = pk2(wk2_w[(size_t)out * HH + in0], wk2_w[(size_t)out * HH + in0 + 1]);
            rb[p] = pk2(wv2_w[(size_t)out * HH + in0], wv2_w[(size_t)out * HH + in0 + 1]);
        }
        a.x = ra[0]; a.y = ra[1]; a.z = ra[2]; a.w = ra[3];
        b.x = rb[0]; b.y = rb[1]; b.z = rb[2]; b.w = rb[3];
        frag[(4 + nt) * 64 + l] = a;
        frag[(10 + nt) * 64 + l] = b;
    }
}

// ---------------- out_w fragment packer: owf[nt*4+kt][64] ----------------
__global__ __launch_bounds__(256) void k_owfrag(
    const float* __restrict__ out_w, uint4* __restrict__ owf)
{
    const int t = threadIdx.x;
    const int l = t & 63;
    const int lm = l & 15, lg = l >> 4;
    #pragma unroll
    for (int it = 0; it < 8; ++it) {
        const int f = (t >> 6) + it * 4;   // 0..31 = nt*4+kt
        const int nt = f >> 2, kt = f & 3;
        const int n = nt * 16 + lm;
        unsigned r[4];
        #pragma unroll
        for (int p = 0; p < 4; ++p) {
            const int k0 = kt * 32 + lg * 8 + 2 * p;
            r[p] = pk2(out_w[(size_t)n * HD + k0], out_w[(size_t)n * HD + k0 + 1]);
        }
        uint4 o; o.x = r[0]; o.y = r[1]; o.z = r[2]; o.w = r[3];
        owf[f * 64 + l] = o;
    }
}

// ---------------- K2: MFMA edge kernel (bf16-packed LDS staging) ------------
__global__ __launch_bounds__(256, 5) void k_edge_mfma(
    const float* __restrict__ ea, const int* __restrict__ eidx,
    const int* __restrict__ rowv, const int* __restrict__ colv,
    const unsigned* __restrict__ hk_bf, const unsigned* __restrict__ g_bf,
    const float* __restrict__ c0_in, const uint4* __restrict__ frag,
    const float* __restrict__ wk1_b, const float* __restrict__ wk2_b,
    const float* __restrict__ wv1_b, const float* __restrict__ wv2_b,
    float* __restrict__ qkP, unsigned* __restrict__ wvP)
{
    __shared__ unsigned lds[4][64 * USTR];   // 17,408 B
    const int w = threadIdx.x >> 6, l = threadIdx.x & 63;
    const int lm = l & 15, lg = l >> 4;
    unsigned* L = lds[w];
    const int e0 = blockIdx.x * 256 + w * 64;
    const int pos = e0 + l;
    const int row = rowv[pos];
    const int col = colv[pos];

    // A fragments: load original-order f32 ea via eidx, convert to bf16
    uint4 eaf[4][2];
    #pragma unroll
    for (int mt = 0; mt < 4; ++mt) {
        const int ee = eidx[e0 + mt * 16 + lm];
        const float* ep = ea + (size_t)ee * ECD + lg * 8;
        const float4 a0 = *(const float4*)(ep);
        const float4 a1 = *(const float4*)(ep + 4);
        const float4 b0 = *(const float4*)(ep + 32);
        const float4 b1 = *(const float4*)(ep + 36);
        eaf[mt][0].x = pk2f(a0.x, a0.y); eaf[mt][0].y = pk2f(a0.z, a0.w);
        eaf[mt][0].z = pk2f(a1.x, a1.y); eaf[mt][0].w = pk2f(a1.z, a1.w);
        eaf[mt][1].x = pk2f(b0.x, b0.y); eaf[mt][1].y = pk2f(b0.z, b0.w);
        eaf[mt][1].z = pk2f(b1.x, b1.y); eaf[mt][1].w = pk2f(b1.z, b1.w);
    }

    // ================= K path =================
    {
        const float b1a = wk1_b[lm], b1b = wk1_b[16 + lm];
        f32x4 acc[4][2];
        #pragma unroll
        for (int mt = 0; mt < 4; ++mt) {
            acc[mt][0] = f32x4{b1a, b1a, b1a, b1a};
            acc[mt][1] = f32x4{b1b, b1b, b1b, b1b};
        }
        const uint4 f00 = frag[0 * 64 + l], f01 = frag[1 * 64 + l];
        const uint4 f10 = frag[2 * 64 + l], f11 = frag[3 * 64 + l];
        #pragma unroll
        for (int mt = 0; mt < 4; ++mt) {
            acc[mt][0] = __builtin_amdgcn_mfma_f32_16x16x32_bf16(as_bf(eaf[mt][0]), as_bf(f00), acc[mt][0], 0, 0, 0);
            acc[mt][1] = __builtin_amdgcn_mfma_f32_16x16x32_bf16(as_bf(eaf[mt][0]), as_bf(f01), acc[mt][1], 0, 0, 0);
            acc[mt][0] = __builtin_amdgcn_mfma_f32_16x16x32_bf16(as_bf(eaf[mt][1]), as_bf(f10), acc[mt][0], 0, 0, 0);
            acc[mt][1] = __builtin_amdgcn_mfma_f32_16x16x32_bf16(as_bf(eaf[mt][1]), as_bf(f11), acc[mt][1], 0, 0, 0);
        }
        // stage ssp(t1) as packed bf16 (lane pair lm, lm^1 = adjacent cols)
        #pragma unroll
        for (int mt = 0; mt < 4; ++mt)
            #pragma unroll
            for (int nt = 0; nt < 2; ++nt)
                #pragma unroll
                for (int r = 0; r < 4; ++r) {
                    const float v = ssp_f(acc[mt][nt][r]);
                    const float pv = __shfl_xor(v, 1);
                    if (!(lm & 1))
                        L[(mt * 16 + lg * 4 + r) * USTR + nt * 8 + (lm >> 1)] = pk2f(v, pv);
                }

        const float b2a = wk2_b[lm], b2b = wk2_b[16 + lm];
        f32x4 acc2[4][2];
        const uint4 f20 = frag[4 * 64 + l], f21 = frag[5 * 64 + l];
        #pragma unroll
        for (int mt = 0; mt < 4; ++mt) {
            acc2[mt][0] = f32x4{b2a, b2a, b2a, b2a};
            acc2[mt][1] = f32x4{b2b, b2b, b2b, b2b};
            uint4 a2;
            a2.x = L[(mt * 16 + lm) * USTR + lg * 4 + 0];
            a2.y = L[(mt * 16 + lm) * USTR + lg * 4 + 1];
            a2.z = L[(mt * 16 + lm) * USTR + lg * 4 + 2];
            a2.w = L[(mt * 16 + lm) * USTR + lg * 4 + 3];
            acc2[mt][0] = __builtin_amdgcn_mfma_f32_16x16x32_bf16(as_bf(a2), as_bf(f20), acc2[mt][0], 0, 0, 0);
            acc2[mt][1] = __builtin_amdgcn_mfma_f32_16x16x32_bf16(as_bf(a2), as_bf(f21), acc2[mt][1], 0, 0, 0);
        }
        // stage Wk as packed bf16
        #pragma unroll
        for (int mt = 0; mt < 4; ++mt)
            #pragma unroll
            for (int nt = 0; nt < 2; ++nt)
                #pragma unroll
                for (int r = 0; r < 4; ++r) {
                    const float v = acc2[mt][nt][r];
                    const float pv = __shfl_xor(v, 1);
                    if (!(lm & 1))
                        L[(mt * 16 + lg * 4 + r) * USTR + nt * 8 + (lm >> 1)] = pk2f(v, pv);
                }
    }

    // per-edge Wk (packed) into registers
    unsigned wku[16];
    #pragma unroll
    for (int j = 0; j < 16; ++j) wku[j] = L[l * USTR + j];

    {
        const uint4* hkp = (const uint4*)(hk_bf + (size_t)col * 64);
        const uint4* gp  = (const uint4*)(g_bf  + (size_t)row * 64);
        const float4 c0v = *(const float4*)(c0_in + (size_t)row * NHD);
        #pragma unroll
        for (int h = 0; h < NHD; ++h) {
            float s = 0.f;
            #pragma unroll
            for (int q = 0; q < 4; ++q) {
                const uint4 ku = hkp[h * 4 + q];
                const uint4 gu = gp[h * 4 + q];
                float ka, kb, ga, gb, w0, w1;
                unp2(ku.x, ka, kb); unp2(gu.x, ga, gb); unp2(wku[q * 4 + 0], w0, w1);
                s = fmaf(w0 * ka, ga, s);
                s = fmaf(w1 * kb, gb, s);
                unp2(ku.y, ka, kb); unp2(gu.y, ga, gb); unp2(wku[q * 4 + 1], w0, w1);
                s = fmaf(w0 * ka, ga, s);
                s = fmaf(w1 * kb, gb, s);
                unp2(ku.z, ka, kb); unp2(gu.z, ga, gb); unp2(wku[q * 4 + 2], w0, w1);
                s = fmaf(w0 * ka, ga, s);
                s = fmaf(w1 * kb, gb, s);
                unp2(ku.w, ka, kb); unp2(gu.w, ga, gb); unp2(wku[q * 4 + 3], w0, w1);
                s = fmaf(w0 * ka, ga, s);
                s = fmaf(w1 * kb, gb, s);
            }
            const float c0h = (h == 0) ? c0v.x : (h == 1) ? c0v.y : (h == 2) ? c0v.z : c0v.w;
            qkP[(size_t)h * EE + pos] = s + c0h;
        }
    }

    // ================= V path =================
    {
        const float b1a = wv1_b[lm], b1b = wv1_b[16 + lm];
        f32x4 acc[4][2];
        #pragma unroll
        for (int mt = 0; mt < 4; ++mt) {
            acc[mt][0] = f32x4{b1a, b1a, b1a, b1a};
            acc[mt][1] = f32x4{b1b, b1b, b1b, b1b};
        }
        const uint4 f00 = frag[6 * 64 + l], f01 = frag[7 * 64 + l];
        const uint4 f10 = frag[8 * 64 + l], f11 = frag[9 * 64 + l];
        #pragma unroll
        for (int mt = 0; mt < 4; ++mt) {
            acc[mt][0] = __builtin_amdgcn_mfma_f32_16x16x32_bf16(as_bf(eaf[mt][0]), as_bf(f00), acc[mt][0], 0, 0, 0);
            acc[mt][1] = __builtin_amdgcn_mfma_f32_16x16x32_bf16(as_bf(eaf[mt][0]), as_bf(f01), acc[mt][1], 0, 0, 0);
            acc[mt][0] = __builtin_amdgcn_mfma_f32_16x16x32_bf16(as_bf(eaf[mt][1]), as_bf(f10), acc[mt][0], 0, 0, 0);
            acc[mt][1] = __builtin_amdgcn_mfma_f32_16x16x32_bf16(as_bf(eaf[mt][1]), as_bf(f11), acc[mt][1], 0, 0, 0);
        }
        #pragma unroll
        for (int mt = 0; mt < 4; ++mt)
            #pragma unroll
            for (int nt = 0; nt < 2; ++nt)
                #pragma unroll
                for (int r = 0; r < 4; ++r) {
                    const float v = ssp_f(acc[mt][nt][r]);
                    const float pv = __shfl_xor(v, 1);
                    if (!(lm & 1))
                        L[(mt * 16 + lg * 4 + r) * USTR + nt * 8 + (lm >> 1)] = pk2f(v, pv);
                }

        const float b2a = wv2_b[lm], b2b = wv2_b[16 + lm];
        f32x4 acc2[4][2];
        const uint4 f20 = frag[10 * 64 + l], f21 = frag[11 * 64 + l];
        #pragma unroll
        for (int mt = 0; mt < 4; ++mt) {
            acc2[mt][0] = f32x4{b2a, b2a, b2a, b2a};
            acc2[mt][1] = f32x4{b2b, b2b, b2b, b2b};
            uint4 a2;
            a2.x = L[(mt * 16 + lm) * USTR + lg * 4 + 0];
            a2.y = L[(mt * 16 + lm) * USTR + lg * 4 + 1];
            a2.z = L[(mt * 16 + lm) * USTR + lg * 4 + 2];
            a2.w = L[(mt * 16 + lm) * USTR + lg * 4 + 3];
            acc2[mt][0] = __builtin_amdgcn_mfma_f32_16x16x32_bf16(as_bf(a2), as_bf(f20), acc2[mt][0], 0, 0, 0);
            acc2[mt][1] = __builtin_amdgcn_mfma_f32_16x16x32_bf16(as_bf(a2), as_bf(f21), acc2[mt][1], 0, 0, 0);
        }
        // stage Wv as packed bf16 (byte-identical to prior pk2f output)
        #pragma unroll
        for (int mt = 0; mt < 4; ++mt)
            #pragma unroll
            for (int nt = 0; nt < 2; ++nt)
                #pragma unroll
                for (int r = 0; r < 4; ++r) {
                    const float v = acc2[mt][nt][r];
                    const float pv = __shfl_xor(v, 1);
                    if (!(lm & 1))
                        L[(mt * 16 + lg * 4 + r) * USTR + nt * 8 + (lm >> 1)] = pk2f(v, pv);
                }
    }

    // coalesced Wv store: direct copy of packed uints
    #pragma unroll
    for (int k = 0; k < 16; ++k) {
        const int f = k * 64 + l;
        const int pr = f >> 4, i = f & 15;
        wvP[(size_t)e0 * 16 + f] = L[pr * USTR + i];
    }
}

// ---------------- K3: fused aggregation + wvl matvec + LN2 + ssp ------------
__global__ __launch_bounds__(256) void k_aggr_tail(
    const float* __restrict__ qkP, const unsigned* __restrict__ wvP,
    const unsigned* __restrict__ hv_bf, const int* __restrict__ colv,
    const int* __restrict__ base, const int* __restrict__ deg,
    const float* __restrict__ x,
    const float* __restrict__ wvl_w, const float* __restrict__ wvl_b,
    const float* __restrict__ ln2_g, const float* __restrict__ ln2_b,
    float* __restrict__ x2P, unsigned* __restrict__ sbf)
{
    __shared__ float swvl[HH * 34];
    __shared__ float su[4][HD];
    for (int idx = threadIdx.x; idx < HH * HH; idx += 256)
        swvl[(idx >> 5) * 34 + (idx & 31)] = wvl_w[idx];
    __syncthreads();

    const int w = threadIdx.x >> 6, l = threadIdx.x & 63;
    const int h = l >> 4, i = l & 15;
    const int t0 = 2 * l;
    const float2 lg2 = *(const float2*)(ln2_g + t0);
    const float2 lb2 = *(const float2*)(ln2_b + t0);
    const int j0 = 2 * i;
    const float2 wb2 = *(const float2*)(wvl_b + j0);
    float* sb = su[w];

    for (int n = blockIdx.x * 4 + w; n < NN; n += 2048 * 4) {
        const int b0 = base[n];
        const int dn = deg[n];
        const float2 xv = *(const float2*)(x + (size_t)n * HD + t0);

        float acc0 = 0.f, acc1 = 0.f;
        if (dn > 0) {
            const float* qkh = qkP + (size_t)h * EE + b0;
            const int emax = b0 + dn - 1;
            float m = -3.0e38f;
            for (int c = i; c < dn; c += 16) m = fmaxf(m, qkh[c]);
            #pragma unroll
            for (int off = 1; off < 16; off <<= 1)
                m = fmaxf(m, __shfl_xor(m, off));
            float den = 0.f;
            for (int c = i; c < dn; c += 16) den += __expf(qkh[c] - m);
            #pragma unroll
            for (int off = 1; off < 16; off <<= 1) den += __shfl_xor(den, off);
            const float rden = (den > 0.f) ? 1.0f / den : 0.f;
            for (int c0 = 0; c0 < dn; c0 += 16) {
                const int tn = (dn - c0 < 16) ? (dn - c0) : 16;
                float ex = 0.f; int cq = 0;
                if (i < tn) {
                    ex = __expf(qkh[c0 + i] - m) * rden;
                    cq = colv[b0 + c0 + i];
                }
                const int t4 = (tn + 3) & ~3;
                for (int i2 = 0; i2 < t4; i2 += 4) {
                    #pragma unroll
                    for (int u = 0; u < 4; ++u) {
                        const int src = (l & 48) | (i2 + u);
                        const float wgt = __shfl(ex, src);
                        const int ce = __shfl(cq, src);
                        int ep = b0 + c0 + i2 + u;
                        ep = (ep > emax) ? emax : ep;
                        const unsigned hvv = hv_bf[(size_t)ce * 64 + l];
                        const unsigned wvv = wvP[(size_t)ep * 16 + i];
                        float ha, hb, wa, wb;
                        unp2(hvv, ha, hb); unp2(wvv, wa, wb);
                        acc0 = fmaf(wgt, wa * ha, acc0);
                        acc1 = fmaf(wgt, wb * hb, acc1);
                    }
                }
            }
        }

        *(float2*)(sb + t0) = make_float2(acc0, acc1);

        float ag0 = 0.f, ag1 = 0.f;
        if (dn > 0) {
            ag0 = wb2.x; ag1 = wb2.y;
            const float* uh = sb + h * HH;
            const float* r0 = swvl + j0 * 34;
            const float* r1 = r0 + 34;
            #pragma unroll
            for (int q = 0; q < 16; ++q) {
                const float2 u  = *(const float2*)(uh + 2 * q);
                const float2 a  = *(const float2*)(r0 + 2 * q);
                const float2 bb = *(const float2*)(r1 + 2 * q);
                ag0 = fmaf(u.x, a.x, ag0);  ag0 = fmaf(u.y, a.y, ag0);
                ag1 = fmaf(u.x, bb.x, ag1); ag1 = fmaf(u.y, bb.y, ag1);
            }
        }
        const float x20 = ag0 + xv.x;
        const float x21 = ag1 + xv.y;

        float s1 = x20 + x21, s2 = x20 * x20 + x21 * x21;
        #pragma unroll
        for (int off = 1; off < 64; off <<= 1) {
            s1 += __shfl_xor(s1, off);
            s2 += __shfl_xor(s2, off);
        }
        const float mean = s1 * (1.0f / HD);
        const float var  = s2 * (1.0f / HD) - mean * mean;
        const float rstd = rsqrtf(var + 1e-5f);
        const float ss0 = ssp_f((x20 - mean) * rstd * lg2.x + lb2.x);
        const float ss1 = ssp_f((x21 - mean) * rstd * lg2.y + lb2.y);

        *(float2*)(x2P + (size_t)n * HD + t0) = make_float2(x20, x21);
        sbf[(size_t)n * 64 + l] = pk2(ss0, ss1);
    }
}

// ---------------- K3c: MFMA out-GEMM: out = sbf @ out_w^T + out_b + x2 ------
__global__ __launch_bounds__(256) void k_tail_gemm(
    const unsigned short* __restrict__ sbf, const float* __restrict__ x2P,
    const uint4* __restrict__ owf, const float* __restrict__ out_b,
    float* __restrict__ out)
{
    const int w = threadIdx.x >> 6, l = threadIdx.x & 63;
    const int lm = l & 15, lg = l >> 4;
    const int tile = blockIdx.x * 4 + w;
    if (tile * 16 >= NN) return;
    const int n0 = tile * 16;

    uint4 af[4];
    #pragma unroll
    for (int kt = 0; kt < 4; ++kt)
        af[kt] = *(const uint4*)(sbf + (size_t)(n0 + lm) * HD + kt * 32 + lg * 8);

    f32x4 acc[8];
    #pragma unroll
    for (int nt = 0; nt < 8; ++nt) {
        const float b = out_b[nt * 16 + lm];
        acc[nt] = f32x4{b, b, b, b};
    }
    #pragma unroll
    for (int kt = 0; kt < 4; ++kt) {
        #pragma unroll
        for (int nt = 0; nt < 8; ++nt)
            acc[nt] = __builtin_amdgcn_mfma_f32_16x16x32_bf16(
                as_bf(af[kt]), as_bf(owf[(nt * 4 + kt) * 64 + l]), acc[nt], 0, 0, 0);
    }
    #pragma unroll
    for (int nt = 0; nt < 8; ++nt)
        #pragma unroll
        for (int r = 0; r < 4; ++r) {
            const size_t idx = (size_t)(n0 + lg * 4 + r) * HD + nt * 16 + lm;
            out[idx] = acc[nt][r] + x2P[idx];
        }
}

extern "C" void kernel_launch(void* const* d_in, const int* in_sizes, int n_in,
                              void* d_out, int out_size, void* d_ws, size_t ws_size,
                              hipStream_t stream) {
    const float* x         = (const float*)d_in[0];
    const float* edge_attr = (const float*)d_in[1];
    const int*   edge_index= (const int*)  d_in[2];
    const float* k_w   = (const float*)d_in[3];
    const float* q_w   = (const float*)d_in[4];
    const float* v_w   = (const float*)d_in[5];
    const float* wk1_w = (const float*)d_in[6];
    const float* wk1_b = (const float*)d_in[7];
    const float* wk2_w = (const float*)d_in[8];
    const float* wk2_b = (const float*)d_in[9];
    const float* wkl_w = (const float*)d_in[10];
    const float* wkl_b = (const float*)d_in[11];
    const float* wv1_w = (const float*)d_in[12];
    const float* wv1_b = (const float*)d_in[13];
    const float* wv2_w = (const float*)d_in[14];
    const float* wv2_b = (const float*)d_in[15];
    const float* wvl_w = (const float*)d_in[16];
    const float* wvl_b = (const float*)d_in[17];
    const float* out_w = (const float*)d_in[18];
    const float* out_b = (const float*)d_in[19];
    const float* ln1_g = (const float*)d_in[20];
    const float* ln1_b = (const float*)d_in[21];
    const float* ln2_g = (const float*)d_in[22];
    const float* ln2_b = (const float*)d_in[23];

    char* ws = (char*)d_ws;
    unsigned* hk_bf = (unsigned*)ws;            ws += (size_t)NN * 64 * 4;
    unsigned* hv_bf = (unsigned*)ws;            ws += (size_t)NN * 64 * 4;
    unsigned* g_bf  = (unsigned*)ws;            ws += (size_t)NN * 64 * 4;
    float* c0  = (float*)ws;                    ws += (size_t)NN * NHD * 4;
    float* qkP = (float*)ws;                    ws += (size_t)NHD * EE * 4;
    unsigned* wvP = (unsigned*)ws;              ws += (size_t)EE * 16 * 4;
    uint4* fragbuf = (uint4*)ws;                ws += (size_t)12 * 64 * 16;
    uint4* owfbuf  = (uint4*)ws;                ws += (size_t)32 * 64 * 16;
    uint4* pfbuf   = (uint4*)ws;                ws += (size_t)3 * 512 * 16;
    float* cw      = (float*)ws;                ws += (size_t)512 * 4;
    float* x2P = (float*)ws;                    ws += (size_t)NN * HD * 4;
    unsigned* sbf = (unsigned*)ws;              ws += (size_t)NN * 64 * 4;
    int* deg    = (int*)ws;                     ws += (size_t)NN * 4;
    int* base   = (int*)ws;                     ws += (size_t)NN * 4;
    int* cursor = (int*)ws;                     ws += (size_t)NN * 4;
    int* bsum   = (int*)ws;                     ws += (size_t)SCAN_B * 4;
    int* eidx   = (int*)ws;                     ws += (size_t)EE * 4;
    int* rowv   = (int*)ws;                     ws += (size_t)EE * 4;
    int* colv   = (int*)ws;                     ws += (size_t)EE * 4;

    (void)hipMemsetAsync(deg, 0, (size_t)NN * 4, stream);

    k_wfrag<<<1, 256, 0, stream>>>(wk1_w, wk2_w, wv1_w, wv2_w, fragbuf);
    k_owfrag<<<1, 256, 0, stream>>>(out_w, owfbuf);
    k_pwfrag<<<1, 256, 0, stream>>>(k_w, v_w, q_w, wkl_w, wkl_b, pfbuf, cw);
    k_ln1proj<<<1024, 256, 0, stream>>>(x, ln1_g, ln1_b, cw, pfbuf, c0,
        (unsigned short*)hk_bf, (unsigned short*)hv_bf, (unsigned short*)g_bf);
    k_deg<<<1024, 256, 0, stream>>>(edge_index, deg);
    k_scan_block<<<NBLK, SCAN_B, 0, stream>>>(deg, base, bsum);
    k_scan_top<<<1, SCAN_B, 0, stream>>>(bsum);
    k_scan_add<<<NBLK, SCAN_B, 0, stream>>>(base, bsum, cursor);
    k_scatter<<<1024, 256, 0, stream>>>(edge_index, cursor, eidx, rowv, colv);
    k_edge_mfma<<<EE / 256, 256, 0, stream>>>(edge_attr, eidx, rowv, colv,
        hk_bf, g_bf, c0, fragbuf,
        wk1_b, wk2_b, wv1_b, wv2_b, qkP, wvP);
    k_aggr_tail<<<2048, 256, 0, stream>>>(qkP, wvP, hv_bf, colv, base, deg,
        x, wvl_w, wvl_b, ln2_g, ln2_b, x2P, sbf);
    k_tail_gemm<<<(NN / 16 + 3) / 4, 256, 0, stream>>>(
        (const unsigned short*)sbf, x2P, owfbuf, out_b, (float*)d_out);
}

// Round 18
// 333.407 us; speedup vs baseline: 1.2797x; 1.2797x over previous
//
#include <hip/hip_runtime.h>
#include <math.h>

#define NN 50000
#define EE 640000
#define HD 128
#define ECD 64
#define NHD 4
#define HH 32
#define SCAN_B 256
#define NBLK ((NN + SCAN_B - 1) / SCAN_B)   // 196
#define USTR 17   // LDS row stride in uints (32 bf16 = 16 uints + 1 pad)
#define NTILE (NN / 16)                     // 3125 (exact)

typedef short bf16x8 __attribute__((ext_vector_type(8)));
typedef float f32x4 __attribute__((ext_vector_type(4)));

__device__ __forceinline__ float ssp_f(float v) {
    return fmaxf(v, 0.0f) + __logf(1.0f + __expf(-fabsf(v))) - 0.69314718055994531f;
}
__device__ __forceinline__ unsigned f2bf_u(float f) {
    unsigned u = __float_as_uint(f);
    unsigned r = ((u >> 16) & 1u) + 0x7FFFu;
    return (u + r) >> 16;
}
__device__ __forceinline__ unsigned pk2(float a, float b) {
    return f2bf_u(a) | (f2bf_u(b) << 16);
}
__device__ __forceinline__ unsigned f2bf_f(float f) {
    return (__float_as_uint(f) + 0x8000u) >> 16;
}
__device__ __forceinline__ unsigned pk2f(float a, float b) {
    return f2bf_f(a) | (f2bf_f(b) << 16);
}
__device__ __forceinline__ void unp2(unsigned u, float& a, float& b) {
    a = __uint_as_float(u << 16);
    b = __uint_as_float(u & 0xffff0000u);
}
__device__ __forceinline__ bf16x8 as_bf(uint4 u) {
    union { uint4 a; bf16x8 b; } c; c.a = u; return c.b;
}

// ---------------- projection weight packer ----------------
__global__ __launch_bounds__(256) void k_pwfrag(
    const float* __restrict__ kw, const float* __restrict__ vw,
    const float* __restrict__ qw, const float* __restrict__ wklw,
    const float* __restrict__ wklb,
    uint4* __restrict__ pf, float* __restrict__ cw)
{
    const int t = threadIdx.x;
    #pragma unroll
    for (int it = 0; it < 6; ++it) {
        const int f = t + it * 256;      // 0..1535
        const int tg = f >> 9;
        const int rem = f & 511;
        const int nt = rem >> 6, l = rem & 63;
        const int lm = l & 15, lg = l >> 4;
        const int h = nt >> 1, od = (nt & 1) * 16 + lm;
        float val[8];
        if (tg == 2) {
            #pragma unroll
            for (int j = 0; j < 8; ++j) {
                float s = 0.f;
                for (int j2 = 0; j2 < 32; ++j2)
                    s += qw[(size_t)(h * 32 + j2) * 32 + lg * 8 + j] * wklw[j2 * 32 + od];
                val[j] = s;
            }
        } else {
            const float* wp = (tg == 0) ? kw : vw;
            #pragma unroll
            for (int j = 0; j < 8; ++j)
                val[j] = wp[(size_t)(h * 32 + od) * 32 + lg * 8 + j];
        }
        uint4 o;
        o.x = pk2(val[0], val[1]); o.y = pk2(val[2], val[3]);
        o.z = pk2(val[4], val[5]); o.w = pk2(val[6], val[7]);
        pf[f] = o;
    }
    #pragma unroll
    for (int d2 = 0; d2 < 2; ++d2) {
        const int idx = t * 2 + d2;     // 0..511
        const int h = idx >> 5, d = idx & 31;
        float s = 0.f;
        for (int j = 0; j < 32; ++j)
            s += qw[(size_t)(h * 32 + j) * 32 + d] * wklb[j];
        cw[idx] = s;
    }
}

// ---------------- K1: fused LN1 + c0 + MFMA projections ---------------------
__global__ __launch_bounds__(256) void k_ln1proj(
    const float* __restrict__ x, const float* __restrict__ ln1_g,
    const float* __restrict__ ln1_b, const float* __restrict__ cw,
    const uint4* __restrict__ pf, float* __restrict__ c0_out,
    unsigned short* __restrict__ hk16, unsigned short* __restrict__ hv16,
    unsigned short* __restrict__ g16)
{
    __shared__ unsigned ylds[16][68];   // 16 nodes x 64 uints, stride 68
    const int w = threadIdx.x >> 6, l = threadIdx.x & 63;
    const int lm = l & 15, lg = l >> 4;
    const int t0 = 2 * l;
    const float2 lg2 = *(const float2*)(ln1_g + t0);
    const float2 lb2 = *(const float2*)(ln1_b + t0);
    const float2 cw2 = *(const float2*)(cw + t0);

    for (int tile = blockIdx.x; tile < NTILE; tile += 1024) {
        const int n0 = tile * 16;
        __syncthreads();   // previous iteration's readers done
        #pragma unroll
        for (int it = 0; it < 4; ++it) {
            const int n = n0 + w * 4 + it;
            const float2 xv = *(const float2*)(x + (size_t)n * HD + t0);
            float s1 = xv.x + xv.y;
            float s2 = xv.x * xv.x + xv.y * xv.y;
            #pragma unroll
            for (int off = 1; off < 64; off <<= 1) {
                s1 += __shfl_xor(s1, off);
                s2 += __shfl_xor(s2, off);
            }
            const float mean = s1 * (1.0f / HD);
            const float var  = s2 * (1.0f / HD) - mean * mean;
            const float rstd = rsqrtf(var + 1e-5f);
            const float y0 = (xv.x - mean) * rstd * lg2.x + lb2.x;
            const float y1 = (xv.y - mean) * rstd * lg2.y + lb2.y;
            ylds[w * 4 + it][l] = pk2(y0, y1);
            float p = y0 * cw2.x + y1 * cw2.y;
            #pragma unroll
            for (int off = 1; off < 16; off <<= 1) p += __shfl_xor(p, off);
            if ((l & 15) == 0) c0_out[n * NHD + (l >> 4)] = p;
        }
        __syncthreads();
        // wave w's A fragment: head w, rows=nodes lm, k-slots lg*8..+7
        uint4 am;
        am.x = ylds[lm][w * 16 + lg * 4 + 0];
        am.y = ylds[lm][w * 16 + lg * 4 + 1];
        am.z = ylds[lm][w * 16 + lg * 4 + 2];
        am.w = ylds[lm][w * 16 + lg * 4 + 3];
        #pragma unroll
        for (int tg = 0; tg < 3; ++tg) {
            unsigned short* o = (tg == 0) ? hk16 : (tg == 1) ? hv16 : g16;
            #pragma unroll
            for (int q = 0; q < 2; ++q) {
                const int nt = 2 * w + q;
                f32x4 acc = f32x4{0.f, 0.f, 0.f, 0.f};
                acc = __builtin_amdgcn_mfma_f32_16x16x32_bf16(
                    as_bf(am), as_bf(pf[tg * 512 + nt * 64 + l]), acc, 0, 0, 0);
                #pragma unroll
                for (int r = 0; r < 4; ++r)
                    o[(size_t)(n0 + lg * 4 + r) * HD + nt * 16 + lm] =
                        (unsigned short)f2bf_u(acc[r]);
            }
        }
    }
}

// ---------------- CSR build ----------------
__global__ __launch_bounds__(256) void k_deg(
    const int* __restrict__ edge_index, int* __restrict__ deg)
{
    for (int e = blockIdx.x * blockDim.x + threadIdx.x; e < EE;
         e += gridDim.x * blockDim.x)
        atomicAdd(&deg[edge_index[e]], 1);
}

__global__ __launch_bounds__(SCAN_B) void k_scan_block(
    const int* __restrict__ deg, int* __restrict__ base, int* __restrict__ bsum)
{
    const int i = blockIdx.x * SCAN_B + threadIdx.x;
    const int v = (i < NN) ? deg[i] : 0;
    __shared__ int s[SCAN_B];
    s[threadIdx.x] = v;
    __syncthreads();
    for (int off = 1; off < SCAN_B; off <<= 1) {
        int t = (threadIdx.x >= off) ? s[threadIdx.x - off] : 0;
        __syncthreads();
        s[threadIdx.x] += t;
        __syncthreads();
    }
    if (i < NN) base[i] = s[threadIdx.x] - v;
    if (threadIdx.x == SCAN_B - 1) bsum[blockIdx.x] = s[SCAN_B - 1];
}

__global__ __launch_bounds__(SCAN_B) void k_scan_top(int* __restrict__ bsum)
{
    const int i = threadIdx.x;
    const int v = (i < NBLK) ? bsum[i] : 0;
    __shared__ int s[SCAN_B];
    s[i] = v;
    __syncthreads();
    for (int off = 1; off < SCAN_B; off <<= 1) {
        int t = (i >= off) ? s[i - off] : 0;
        __syncthreads();
        s[i] += t;
        __syncthreads();
    }
    if (i < NBLK) bsum[i] = s[i] - v;
}

__global__ __launch_bounds__(SCAN_B) void k_scan_add(
    int* __restrict__ base, const int* __restrict__ bsum, int* __restrict__ cursor)
{
    const int i = blockIdx.x * SCAN_B + threadIdx.x;
    if (i < NN) {
        const int b = base[i] + bsum[i >> 8];
        base[i] = b;
        cursor[i] = b;
    }
}

__global__ __launch_bounds__(256) void k_scatter(
    const int* __restrict__ edge_index, int* __restrict__ cursor,
    int* __restrict__ eidx, int* __restrict__ rowv, int* __restrict__ colv)
{
    for (int e = blockIdx.x * blockDim.x + threadIdx.x; e < EE;
         e += gridDim.x * blockDim.x) {
        const int r = edge_index[e];
        const int pos = atomicAdd(&cursor[r], 1);
        eidx[pos] = e;
        rowv[pos] = r;
        colv[pos] = edge_index[EE + e];
    }
}

// ---------------- edge-MLP weight fragment packer (1 block) ----------------
__global__ __launch_bounds__(256) void k_wfrag(
    const float* __restrict__ wk1_w, const float* __restrict__ wk2_w,
    const float* __restrict__ wv1_w, const float* __restrict__ wv2_w,
    uint4* __restrict__ frag)
{
    const int t = threadIdx.x;
    const int l = t & 63;
    const int lm = l & 15, lg = l >> 4;
    {
        const int f = t >> 6;          // 0..3
        const int kt = f >> 1, nt = f & 1;
        const int out = nt * 16 + lm;
        uint4 a, b;
        unsigned ra[4], rb[4];
        #pragma unroll
        for (int p = 0; p < 4; ++p) {
            const int in0 = kt * 32 + lg * 8 + 2 * p;
            ra[p] = pk2(wk1_w[(size_t)out * ECD + in0], wk1_w[(size_t)out * ECD + in0 + 1]);
            rb[p] = pk2(wv1_w[(size_t)out * ECD + in0], wv1_w[(size_t)out * ECD + in0 + 1]);
        }
        a.x = ra[0]; a.y = ra[1]; a.z = ra[2]; a.w = ra[3];
        b.x = rb[0]; b.y = rb[1]; b.z = rb[2]; b.w = rb[3];
        frag[f * 64 + l] = a;
        frag[(6 + f) * 64 + l] = b;
    }
    if (t < 128) {
        const int nt = t >> 6;
        const int out = nt * 16 + lm;
        uint4 a, b;
        unsigned ra[4], rb[4];
        #pragma unroll
        for (int p = 0; p < 4; ++p) {
            const int in0 = lg * 8 + 2 * p;
            ra[p] = pk2(wk2_w[(size_t)out * HH + in0], wk2_w[(size_t)out * HH + in0 + 1]);
            rb[p] = pk2(wv2_w[(size_t)out * HH + in0], wv2_w[(size_t)out * HH + in0 + 1]);
        }
        a.x = ra[0]; a.y = ra[1]; a.z = ra[2]; a.w = ra[3];
        b.x = rb[0]; b.y = rb[1]; b.z = rb[2]; b.w = rb[3];
        frag[(4 + nt) * 64 + l] = a;
        frag[(10 + nt) * 64 + l] = b;
    }
}

// ---------------- out_w fragment packer: owf[nt*4+kt][64] ----------------
__global__ __launch_bounds__(256) void k_owfrag(
    const float* __restrict__ out_w, uint4* __restrict__ owf)
{
    const int t = threadIdx.x;
    const int l = t & 63;
    const int lm = l & 15, lg = l >> 4;
    #pragma unroll
    for (int it = 0; it < 8; ++it) {
        const int f = (t >> 6) + it * 4;   // 0..31 = nt*4+kt
        const int nt = f >> 2, kt = f & 3;
        const int n = nt * 16 + lm;
        unsigned r[4];
        #pragma unroll
        for (int p = 0; p < 4; ++p) {
            const int k0 = kt * 32 + lg * 8 + 2 * p;
            r[p] = pk2(out_w[(size_t)n * HD + k0], out_w[(size_t)n * HD + k0 + 1]);
        }
        uint4 o; o.x = r[0]; o.y = r[1]; o.z = r[2]; o.w = r[3];
        owf[f * 64 + l] = o;
    }
}

// ---------------- K2: MFMA edge kernel (bf16-packed LDS staging) ------------
__global__ __launch_bounds__(256) void k_edge_mfma(
    const float* __restrict__ ea, const int* __restrict__ eidx,
    const int* __restrict__ rowv, const int* __restrict__ colv,
    const unsigned* __restrict__ hk_bf, const unsigned* __restrict__ g_bf,
    const float* __restrict__ c0_in, const uint4* __restrict__ frag,
    const float* __restrict__ wk1_b, const float* __restrict__ wk2_b,
    const float* __restrict__ wv1_b, const float* __restrict__ wv2_b,
    float* __restrict__ qkP, unsigned* __restrict__ wvP)
{
    __shared__ unsigned lds[4][64 * USTR];   // 17,408 B
    const int w = threadIdx.x >> 6, l = threadIdx.x & 63;
    const int lm = l & 15, lg = l >> 4;
    unsigned* L = lds[w];
    const int e0 = blockIdx.x * 256 + w * 64;
    const int pos = e0 + l;
    const int row = rowv[pos];
    const int col = colv[pos];

    // A fragments: load original-order f32 ea via eidx, convert to bf16
    uint4 eaf[4][2];
    #pragma unroll
    for (int mt = 0; mt < 4; ++mt) {
        const int ee = eidx[e0 + mt * 16 + lm];
        const float* ep = ea + (size_t)ee * ECD + lg * 8;
        const float4 a0 = *(const float4*)(ep);
        const float4 a1 = *(const float4*)(ep + 4);
        const float4 b0 = *(const float4*)(ep + 32);
        const float4 b1 = *(const float4*)(ep + 36);
        eaf[mt][0].x = pk2f(a0.x, a0.y); eaf[mt][0].y = pk2f(a0.z, a0.w);
        eaf[mt][0].z = pk2f(a1.x, a1.y); eaf[mt][0].w = pk2f(a1.z, a1.w);
        eaf[mt][1].x = pk2f(b0.x, b0.y); eaf[mt][1].y = pk2f(b0.z, b0.w);
        eaf[mt][1].z = pk2f(b1.x, b1.y); eaf[mt][1].w = pk2f(b1.z, b1.w);
    }

    // ================= K path =================
    {
        const float b1a = wk1_b[lm], b1b = wk1_b[16 + lm];
        f32x4 acc[4][2];
        #pragma unroll
        for (int mt = 0; mt < 4; ++mt) {
            acc[mt][0] = f32x4{b1a, b1a, b1a, b1a};
            acc[mt][1] = f32x4{b1b, b1b, b1b, b1b};
        }
        const uint4 f00 = frag[0 * 64 + l], f01 = frag[1 * 64 + l];
        const uint4 f10 = frag[2 * 64 + l], f11 = frag[3 * 64 + l];
        #pragma unroll
        for (int mt = 0; mt < 4; ++mt) {
            acc[mt][0] = __builtin_amdgcn_mfma_f32_16x16x32_bf16(as_bf(eaf[mt][0]), as_bf(f00), acc[mt][0], 0, 0, 0);
            acc[mt][1] = __builtin_amdgcn_mfma_f32_16x16x32_bf16(as_bf(eaf[mt][0]), as_bf(f01), acc[mt][1], 0, 0, 0);
            acc[mt][0] = __builtin_amdgcn_mfma_f32_16x16x32_bf16(as_bf(eaf[mt][1]), as_bf(f10), acc[mt][0], 0, 0, 0);
            acc[mt][1] = __builtin_amdgcn_mfma_f32_16x16x32_bf16(as_bf(eaf[mt][1]), as_bf(f11), acc[mt][1], 0, 0, 0);
        }
        // stage ssp(t1) as packed bf16 (lane pair lm, lm^1 = adjacent cols)
        #pragma unroll
        for (int mt = 0; mt < 4; ++mt)
            #pragma unroll
            for (int nt = 0; nt < 2; ++nt)
                #pragma unroll
                for (int r = 0; r < 4; ++r) {
                    const float v = ssp_f(acc[mt][nt][r]);
                    const float pv = __shfl_xor(v, 1);
                    if (!(lm & 1))
                        L[(mt * 16 + lg * 4 + r) * USTR + nt * 8 + (lm >> 1)] = pk2f(v, pv);
                }

        const float b2a = wk2_b[lm], b2b = wk2_b[16 + lm];
        f32x4 acc2[4][2];
        const uint4 f20 = frag[4 * 64 + l], f21 = frag[5 * 64 + l];
        #pragma unroll
        for (int mt = 0; mt < 4; ++mt) {
            acc2[mt][0] = f32x4{b2a, b2a, b2a, b2a};
            acc2[mt][1] = f32x4{b2b, b2b, b2b, b2b};
            uint4 a2;
            a2.x = L[(mt * 16 + lm) * USTR + lg * 4 + 0];
            a2.y = L[(mt * 16 + lm) * USTR + lg * 4 + 1];
            a2.z = L[(mt * 16 + lm) * USTR + lg * 4 + 2];
            a2.w = L[(mt * 16 + lm) * USTR + lg * 4 + 3];
            acc2[mt][0] = __builtin_amdgcn_mfma_f32_16x16x32_bf16(as_bf(a2), as_bf(f20), acc2[mt][0], 0, 0, 0);
            acc2[mt][1] = __builtin_amdgcn_mfma_f32_16x16x32_bf16(as_bf(a2), as_bf(f21), acc2[mt][1], 0, 0, 0);
        }
        // stage Wk as packed bf16
        #pragma unroll
        for (int mt = 0; mt < 4; ++mt)
            #pragma unroll
            for (int nt = 0; nt < 2; ++nt)
                #pragma unroll
                for (int r = 0; r < 4; ++r) {
                    const float v = acc2[mt][nt][r];
                    const float pv = __shfl_xor(v, 1);
                    if (!(lm & 1))
                        L[(mt * 16 + lg * 4 + r) * USTR + nt * 8 + (lm >> 1)] = pk2f(v, pv);
                }
    }

    // per-edge Wk (packed) into registers
    unsigned wku[16];
    #pragma unroll
    for (int j = 0; j < 16; ++j) wku[j] = L[l * USTR + j];

    {
        const uint4* hkp = (const uint4*)(hk_bf + (size_t)col * 64);
        const uint4* gp  = (const uint4*)(g_bf  + (size_t)row * 64);
        const float4 c0v = *(const float4*)(c0_in + (size_t)row * NHD);
        #pragma unroll
        for (int h = 0; h < NHD; ++h) {
            float s = 0.f;
            #pragma unroll
            for (int q = 0; q < 4; ++q) {
                const uint4 ku = hkp[h * 4 + q];
                const uint4 gu = gp[h * 4 + q];
                float ka, kb, ga, gb, w0, w1;
                unp2(ku.x, ka, kb); unp2(gu.x, ga, gb); unp2(wku[q * 4 + 0], w0, w1);
                s = fmaf(w0 * ka, ga, s);
                s = fmaf(w1 * kb, gb, s);
                unp2(ku.y, ka, kb); unp2(gu.y, ga, gb); unp2(wku[q * 4 + 1], w0, w1);
                s = fmaf(w0 * ka, ga, s);
                s = fmaf(w1 * kb, gb, s);
                unp2(ku.z, ka, kb); unp2(gu.z, ga, gb); unp2(wku[q * 4 + 2], w0, w1);
                s = fmaf(w0 * ka, ga, s);
                s = fmaf(w1 * kb, gb, s);
                unp2(ku.w, ka, kb); unp2(gu.w, ga, gb); unp2(wku[q * 4 + 3], w0, w1);
                s = fmaf(w0 * ka, ga, s);
                s = fmaf(w1 * kb, gb, s);
            }
            const float c0h = (h == 0) ? c0v.x : (h == 1) ? c0v.y : (h == 2) ? c0v.z : c0v.w;
            qkP[(size_t)h * EE + pos] = s + c0h;
        }
    }

    // ================= V path =================
    {
        const float b1a = wv1_b[lm], b1b = wv1_b[16 + lm];
        f32x4 acc[4][2];
        #pragma unroll
        for (int mt = 0; mt < 4; ++mt) {
            acc[mt][0] = f32x4{b1a, b1a, b1a, b1a};
            acc[mt][1] = f32x4{b1b, b1b, b1b, b1b};
        }
        const uint4 f00 = frag[6 * 64 + l], f01 = frag[7 * 64 + l];
        const uint4 f10 = frag[8 * 64 + l], f11 = frag[9 * 64 + l];
        #pragma unroll
        for (int mt = 0; mt < 4; ++mt) {
            acc[mt][0] = __builtin_amdgcn_mfma_f32_16x16x32_bf16(as_bf(eaf[mt][0]), as_bf(f00), acc[mt][0], 0, 0, 0);
            acc[mt][1] = __builtin_amdgcn_mfma_f32_16x16x32_bf16(as_bf(eaf[mt][0]), as_bf(f01), acc[mt][1], 0, 0, 0);
            acc[mt][0] = __builtin_amdgcn_mfma_f32_16x16x32_bf16(as_bf(eaf[mt][1]), as_bf(f10), acc[mt][0], 0, 0, 0);
            acc[mt][1] = __builtin_amdgcn_mfma_f32_16x16x32_bf16(as_bf(eaf[mt][1]), as_bf(f11), acc[mt][1], 0, 0, 0);
        }
        #pragma unroll
        for (int mt = 0; mt < 4; ++mt)
            #pragma unroll
            for (int nt = 0; nt < 2; ++nt)
                #pragma unroll
                for (int r = 0; r < 4; ++r) {
                    const float v = ssp_f(acc[mt][nt][r]);
                    const float pv = __shfl_xor(v, 1);
                    if (!(lm & 1))
                        L[(mt * 16 + lg * 4 + r) * USTR + nt * 8 + (lm >> 1)] = pk2f(v, pv);
                }

        const float b2a = wv2_b[lm], b2b = wv2_b[16 + lm];
        f32x4 acc2[4][2];
        const uint4 f20 = frag[10 * 64 + l], f21 = frag[11 * 64 + l];
        #pragma unroll
        for (int mt = 0; mt < 4; ++mt) {
            acc2[mt][0] = f32x4{b2a, b2a, b2a, b2a};
            acc2[mt][1] = f32x4{b2b, b2b, b2b, b2b};
            uint4 a2;
            a2.x = L[(mt * 16 + lm) * USTR + lg * 4 + 0];
            a2.y = L[(mt * 16 + lm) * USTR + lg * 4 + 1];
            a2.z = L[(mt * 16 + lm) * USTR + lg * 4 + 2];
            a2.w = L[(mt * 16 + lm) * USTR + lg * 4 + 3];
            acc2[mt][0] = __builtin_amdgcn_mfma_f32_16x16x32_bf16(as_bf(a2), as_bf(f20), acc2[mt][0], 0, 0, 0);
            acc2[mt][1] = __builtin_amdgcn_mfma_f32_16x16x32_bf16(as_bf(a2), as_bf(f21), acc2[mt][1], 0, 0, 0);
        }
        // stage Wv as packed bf16 (byte-identical to prior pk2f output)
        #pragma unroll
        for (int mt = 0; mt < 4; ++mt)
            #pragma unroll
            for (int nt = 0; nt < 2; ++nt)
                #pragma unroll
                for (int r = 0; r < 4; ++r) {
                    const float v = acc2[mt][nt][r];
                    const float pv = __shfl_xor(v, 1);
                    if (!(lm & 1))
                        L[(mt * 16 + lg * 4 + r) * USTR + nt * 8 + (lm >> 1)] = pk2f(v, pv);
                }
    }

    // coalesced Wv store: direct copy of packed uints
    #pragma unroll
    for (int k = 0; k < 16; ++k) {
        const int f = k * 64 + l;
        const int pr = f >> 4, i = f & 15;
        wvP[(size_t)e0 * 16 + f] = L[pr * USTR + i];
    }
}

// ---------------- K3: fused aggregation + wvl matvec + LN2 + ssp ------------
__global__ __launch_bounds__(256) void k_aggr_tail(
    const float* __restrict__ qkP, const unsigned* __restrict__ wvP,
    const unsigned* __restrict__ hv_bf, const int* __restrict__ colv,
    const int* __restrict__ base, const int* __restrict__ deg,
    const float* __restrict__ x,
    const float* __restrict__ wvl_w, const float* __restrict__ wvl_b,
    const float* __restrict__ ln2_g, const float* __restrict__ ln2_b,
    float* __restrict__ x2P, unsigned* __restrict__ sbf)
{
    __shared__ float swvl[HH * 34];
    __shared__ float su[4][HD];
    for (int idx = threadIdx.x; idx < HH * HH; idx += 256)
        swvl[(idx >> 5) * 34 + (idx & 31)] = wvl_w[idx];
    __syncthreads();

    const int w = threadIdx.x >> 6, l = threadIdx.x & 63;
    const int h = l >> 4, i = l & 15;
    const int t0 = 2 * l;
    const float2 lg2 = *(const float2*)(ln2_g + t0);
    const float2 lb2 = *(const float2*)(ln2_b + t0);
    const int j0 = 2 * i;
    const float2 wb2 = *(const float2*)(wvl_b + j0);
    float* sb = su[w];

    for (int n = blockIdx.x * 4 + w; n < NN; n += 2048 * 4) {
        const int b0 = base[n];
        const int dn = deg[n];
        const float2 xv = *(const float2*)(x + (size_t)n * HD + t0);

        float acc0 = 0.f, acc1 = 0.f;
        if (dn > 0) {
            const float* qkh = qkP + (size_t)h * EE + b0;
            const int emax = b0 + dn - 1;
            float m = -3.0e38f;
            for (int c = i; c < dn; c += 16) m = fmaxf(m, qkh[c]);
            #pragma unroll
            for (int off = 1; off < 16; off <<= 1)
                m = fmaxf(m, __shfl_xor(m, off));
            float den = 0.f;
            for (int c = i; c < dn; c += 16) den += __expf(qkh[c] - m);
            #pragma unroll
            for (int off = 1; off < 16; off <<= 1) den += __shfl_xor(den, off);
            const float rden = (den > 0.f) ? 1.0f / den : 0.f;
            for (int c0 = 0; c0 < dn; c0 += 16) {
                const int tn = (dn - c0 < 16) ? (dn - c0) : 16;
                float ex = 0.f; int cq = 0;
                if (i < tn) {
                    ex = __expf(qkh[c0 + i] - m) * rden;
                    cq = colv[b0 + c0 + i];
                }
                const int t4 = (tn + 3) & ~3;
                for (int i2 = 0; i2 < t4; i2 += 4) {
                    #pragma unroll
                    for (int u = 0; u < 4; ++u) {
                        const int src = (l & 48) | (i2 + u);
                        const float wgt = __shfl(ex, src);
                        const int ce = __shfl(cq, src);
                        int ep = b0 + c0 + i2 + u;
                        ep = (ep > emax) ? emax : ep;
                        const unsigned hvv = hv_bf[(size_t)ce * 64 + l];
                        const unsigned wvv = wvP[(size_t)ep * 16 + i];
                        float ha, hb, wa, wb;
                        unp2(hvv, ha, hb); unp2(wvv, wa, wb);
                        acc0 = fmaf(wgt, wa * ha, acc0);
                        acc1 = fmaf(wgt, wb * hb, acc1);
                    }
                }
            }
        }

        *(float2*)(sb + t0) = make_float2(acc0, acc1);

        float ag0 = 0.f, ag1 = 0.f;
        if (dn > 0) {
            ag0 = wb2.x; ag1 = wb2.y;
            const float* uh = sb + h * HH;
            const float* r0 = swvl + j0 * 34;
            const float* r1 = r0 + 34;
            #pragma unroll
            for (int q = 0; q < 16; ++q) {
                const float2 u  = *(const float2*)(uh + 2 * q);
                const float2 a  = *(const float2*)(r0 + 2 * q);
                const float2 bb = *(const float2*)(r1 + 2 * q);
                ag0 = fmaf(u.x, a.x, ag0);  ag0 = fmaf(u.y, a.y, ag0);
                ag1 = fmaf(u.x, bb.x, ag1); ag1 = fmaf(u.y, bb.y, ag1);
            }
        }
        const float x20 = ag0 + xv.x;
        const float x21 = ag1 + xv.y;

        float s1 = x20 + x21, s2 = x20 * x20 + x21 * x21;
        #pragma unroll
        for (int off = 1; off < 64; off <<= 1) {
            s1 += __shfl_xor(s1, off);
            s2 += __shfl_xor(s2, off);
        }
        const float mean = s1 * (1.0f / HD);
        const float var  = s2 * (1.0f / HD) - mean * mean;
        const float rstd = rsqrtf(var + 1e-5f);
        const float ss0 = ssp_f((x20 - mean) * rstd * lg2.x + lb2.x);
        const float ss1 = ssp_f((x21 - mean) * rstd * lg2.y + lb2.y);

        *(float2*)(x2P + (size_t)n * HD + t0) = make_float2(x20, x21);
        sbf[(size_t)n * 64 + l] = pk2(ss0, ss1);
    }
}

// ---------------- K3c: MFMA out-GEMM: out = sbf @ out_w^T + out_b + x2 ------
__global__ __launch_bounds__(256) void k_tail_gemm(
    const unsigned short* __restrict__ sbf, const float* __restrict__ x2P,
    const uint4* __restrict__ owf, const float* __restrict__ out_b,
    float* __restrict__ out)
{
    const int w = threadIdx.x >> 6, l = threadIdx.x & 63;
    const int lm = l & 15, lg = l >> 4;
    const int tile = blockIdx.x * 4 + w;
    if (tile * 16 >= NN) return;
    const int n0 = tile * 16;

    uint4 af[4];
    #pragma unroll
    for (int kt = 0; kt < 4; ++kt)
        af[kt] = *(const uint4*)(sbf + (size_t)(n0 + lm) * HD + kt * 32 + lg * 8);

    f32x4 acc[8];
    #pragma unroll
    for (int nt = 0; nt < 8; ++nt) {
        const float b = out_b[nt * 16 + lm];
        acc[nt] = f32x4{b, b, b, b};
    }
    #pragma unroll
    for (int kt = 0; kt < 4; ++kt) {
        #pragma unroll
        for (int nt = 0; nt < 8; ++nt)
            acc[nt] = __builtin_amdgcn_mfma_f32_16x16x32_bf16(
                as_bf(af[kt]), as_bf(owf[(nt * 4 + kt) * 64 + l]), acc[nt], 0, 0, 0);
    }
    #pragma unroll
    for (int nt = 0; nt < 8; ++nt)
        #pragma unroll
        for (int r = 0; r < 4; ++r) {
            const size_t idx = (size_t)(n0 + lg * 4 + r) * HD + nt * 16 + lm;
            out[idx] = acc[nt][r] + x2P[idx];
        }
}

extern "C" void kernel_launch(void* const* d_in, const int* in_sizes, int n_in,
                              void* d_out, int out_size, void* d_ws, size_t ws_size,
                              hipStream_t stream) {
    const float* x         = (const float*)d_in[0];
    const float* edge_attr = (const float*)d_in[1];
    const int*   edge_index= (const int*)  d_in[2];
    const float* k_w   = (const float*)d_in[3];
    const float* q_w   = (const float*)d_in[4];
    const float* v_w   = (const float*)d_in[5];
    const float* wk1_w = (const float*)d_in[6];
    const float* wk1_b = (const float*)d_in[7];
    const float* wk2_w = (const float*)d_in[8];
    const float* wk2_b = (const float*)d_in[9];
    const float* wkl_w = (const float*)d_in[10];
    const float* wkl_b = (const float*)d_in[11];
    const float* wv1_w = (const float*)d_in[12];
    const float* wv1_b = (const float*)d_in[13];
    const float* wv2_w = (const float*)d_in[14];
    const float* wv2_b = (const float*)d_in[15];
    const float* wvl_w = (const float*)d_in[16];
    const float* wvl_b = (const float*)d_in[17];
    const float* out_w = (const float*)d_in[18];
    const float* out_b = (const float*)d_in[19];
    const float* ln1_g = (const float*)d_in[20];
    const float* ln1_b = (const float*)d_in[21];
    const float* ln2_g = (const float*)d_in[22];
    const float* ln2_b = (const float*)d_in[23];

    char* ws = (char*)d_ws;
    unsigned* hk_bf = (unsigned*)ws;            ws += (size_t)NN * 64 * 4;
    unsigned* hv_bf = (unsigned*)ws;            ws += (size_t)NN * 64 * 4;
    unsigned* g_bf  = (unsigned*)ws;            ws += (size_t)NN * 64 * 4;
    float* c0  = (float*)ws;                    ws += (size_t)NN * NHD * 4;
    float* qkP = (float*)ws;                    ws += (size_t)NHD * EE * 4;
    unsigned* wvP = (unsigned*)ws;              ws += (size_t)EE * 16 * 4;
    uint4* fragbuf = (uint4*)ws;                ws += (size_t)12 * 64 * 16;
    uint4* owfbuf  = (uint4*)ws;                ws += (size_t)32 * 64 * 16;
    uint4* pfbuf   = (uint4*)ws;                ws += (size_t)3 * 512 * 16;
    float* cw      = (float*)ws;                ws += (size_t)512 * 4;
    float* x2P = (float*)ws;                    ws += (size_t)NN * HD * 4;
    unsigned* sbf = (unsigned*)ws;              ws += (size_t)NN * 64 * 4;
    int* deg    = (int*)ws;                     ws += (size_t)NN * 4;
    int* base   = (int*)ws;                     ws += (size_t)NN * 4;
    int* cursor = (int*)ws;                     ws += (size_t)NN * 4;
    int* bsum   = (int*)ws;                     ws += (size_t)SCAN_B * 4;
    int* eidx   = (int*)ws;                     ws += (size_t)EE * 4;
    int* rowv   = (int*)ws;                     ws += (size_t)EE * 4;
    int* colv   = (int*)ws;                     ws += (size_t)EE * 4;

    (void)hipMemsetAsync(deg, 0, (size_t)NN * 4, stream);

    k_wfrag<<<1, 256, 0, stream>>>(wk1_w, wk2_w, wv1_w, wv2_w, fragbuf);
    k_owfrag<<<1, 256, 0, stream>>>(out_w, owfbuf);
    k_pwfrag<<<1, 256, 0, stream>>>(k_w, v_w, q_w, wkl_w, wkl_b, pfbuf, cw);
    k_ln1proj<<<1024, 256, 0, stream>>>(x, ln1_g, ln1_b, cw, pfbuf, c0,
        (unsigned short*)hk_bf, (unsigned short*)hv_bf, (unsigned short*)g_bf);
    k_deg<<<1024, 256, 0, stream>>>(edge_index, deg);
    k_scan_block<<<NBLK, SCAN_B, 0, stream>>>(deg, base, bsum);
    k_scan_top<<<1, SCAN_B, 0, stream>>>(bsum);
    k_scan_add<<<NBLK, SCAN_B, 0, stream>>>(base, bsum, cursor);
    k_scatter<<<1024, 256, 0, stream>>>(edge_index, cursor, eidx, rowv, colv);
    k_edge_mfma<<<EE / 256, 256, 0, stream>>>(edge_attr, eidx, rowv, colv,
        hk_bf, g_bf, c0, fragbuf,
        wk1_b, wk2_b, wv1_b, wv2_b, qkP, wvP);
    k_aggr_tail<<<2048, 256, 0, stream>>>(qkP, wvP, hv_bf, colv, base, deg,
        x, wvl_w, wvl_b, ln2_g, ln2_b, x2P, sbf);
    k_tail_gemm<<<(NN / 16 + 3) / 4, 256, 0, stream>>>(
        (const unsigned short*)sbf, x2P, owfbuf, out_b, (float*)d_out);
}

// Round 19
// 307.314 us; speedup vs baseline: 1.3884x; 1.0849x over previous
//
#include <hip/hip_runtime.h>
#include <math.h>

#define NN 50000
#define EE 640000
#define HD 128
#define ECD 64
#define NHD 4
#define HH 32
#define SCAN_B 256
#define NBLK ((NN + SCAN_B - 1) / SCAN_B)   // 196
#define LSTR 33
#define NTILE (NN / 16)                     // 3125 (exact)

typedef short bf16x8 __attribute__((ext_vector_type(8)));
typedef float f32x4 __attribute__((ext_vector_type(4)));

__device__ __forceinline__ float ssp_f(float v) {
    return fmaxf(v, 0.0f) + __logf(1.0f + __expf(-fabsf(v))) - 0.69314718055994531f;
}
__device__ __forceinline__ unsigned f2bf_u(float f) {
    unsigned u = __float_as_uint(f);
    unsigned r = ((u >> 16) & 1u) + 0x7FFFu;
    return (u + r) >> 16;
}
__device__ __forceinline__ unsigned pk2(float a, float b) {
    return f2bf_u(a) | (f2bf_u(b) << 16);
}
__device__ __forceinline__ unsigned f2bf_f(float f) {
    return (__float_as_uint(f) + 0x8000u) >> 16;
}
__device__ __forceinline__ unsigned pk2f(float a, float b) {
    return f2bf_f(a) | (f2bf_f(b) << 16);
}
__device__ __forceinline__ void unp2(unsigned u, float& a, float& b) {
    a = __uint_as_float(u << 16);
    b = __uint_as_float(u & 0xffff0000u);
}
__device__ __forceinline__ bf16x8 as_bf(uint4 u) {
    union { uint4 a; bf16x8 b; } c; c.a = u; return c.b;
}

// ---------------- projection weight packer ----------------
__global__ __launch_bounds__(256) void k_pwfrag(
    const float* __restrict__ kw, const float* __restrict__ vw,
    const float* __restrict__ qw, const float* __restrict__ wklw,
    const float* __restrict__ wklb,
    uint4* __restrict__ pf, float* __restrict__ cw)
{
    const int t = threadIdx.x;
    #pragma unroll
    for (int it = 0; it < 6; ++it) {
        const int f = t + it * 256;      // 0..1535
        const int tg = f >> 9;
        const int rem = f & 511;
        const int nt = rem >> 6, l = rem & 63;
        const int lm = l & 15, lg = l >> 4;
        const int h = nt >> 1, od = (nt & 1) * 16 + lm;
        float val[8];
        if (tg == 2) {
            #pragma unroll
            for (int j = 0; j < 8; ++j) {
                float s = 0.f;
                for (int j2 = 0; j2 < 32; ++j2)
                    s += qw[(size_t)(h * 32 + j2) * 32 + lg * 8 + j] * wklw[j2 * 32 + od];
                val[j] = s;
            }
        } else {
            const float* wp = (tg == 0) ? kw : vw;
            #pragma unroll
            for (int j = 0; j < 8; ++j)
                val[j] = wp[(size_t)(h * 32 + od) * 32 + lg * 8 + j];
        }
        uint4 o;
        o.x = pk2(val[0], val[1]); o.y = pk2(val[2], val[3]);
        o.z = pk2(val[4], val[5]); o.w = pk2(val[6], val[7]);
        pf[f] = o;
    }
    #pragma unroll
    for (int d2 = 0; d2 < 2; ++d2) {
        const int idx = t * 2 + d2;     // 0..511
        const int h = idx >> 5, d = idx & 31;
        float s = 0.f;
        for (int j = 0; j < 32; ++j)
            s += qw[(size_t)(h * 32 + j) * 32 + d] * wklb[j];
        cw[idx] = s;
    }
}

// ---------------- K1: fused LN1 + c0 + MFMA projections ---------------------
__global__ __launch_bounds__(256) void k_ln1proj(
    const float* __restrict__ x, const float* __restrict__ ln1_g,
    const float* __restrict__ ln1_b, const float* __restrict__ cw,
    const uint4* __restrict__ pf, float* __restrict__ c0_out,
    unsigned short* __restrict__ hk16, unsigned short* __restrict__ hv16,
    unsigned short* __restrict__ g16)
{
    __shared__ unsigned ylds[16][68];   // 16 nodes x 64 uints, stride 68
    const int w = threadIdx.x >> 6, l = threadIdx.x & 63;
    const int lm = l & 15, lg = l >> 4;
    const int t0 = 2 * l;
    const float2 lg2 = *(const float2*)(ln1_g + t0);
    const float2 lb2 = *(const float2*)(ln1_b + t0);
    const float2 cw2 = *(const float2*)(cw + t0);

    for (int tile = blockIdx.x; tile < NTILE; tile += 1024) {
        const int n0 = tile * 16;
        __syncthreads();   // previous iteration's readers done
        #pragma unroll
        for (int it = 0; it < 4; ++it) {
            const int n = n0 + w * 4 + it;
            const float2 xv = *(const float2*)(x + (size_t)n * HD + t0);
            float s1 = xv.x + xv.y;
            float s2 = xv.x * xv.x + xv.y * xv.y;
            #pragma unroll
            for (int off = 1; off < 64; off <<= 1) {
                s1 += __shfl_xor(s1, off);
                s2 += __shfl_xor(s2, off);
            }
            const float mean = s1 * (1.0f / HD);
            const float var  = s2 * (1.0f / HD) - mean * mean;
            const float rstd = rsqrtf(var + 1e-5f);
            const float y0 = (xv.x - mean) * rstd * lg2.x + lb2.x;
            const float y1 = (xv.y - mean) * rstd * lg2.y + lb2.y;
            ylds[w * 4 + it][l] = pk2(y0, y1);
            float p = y0 * cw2.x + y1 * cw2.y;
            #pragma unroll
            for (int off = 1; off < 16; off <<= 1) p += __shfl_xor(p, off);
            if ((l & 15) == 0) c0_out[n * NHD + (l >> 4)] = p;
        }
        __syncthreads();
        // wave w's A fragment: head w, rows=nodes lm, k-slots lg*8..+7
        uint4 am;
        am.x = ylds[lm][w * 16 + lg * 4 + 0];
        am.y = ylds[lm][w * 16 + lg * 4 + 1];
        am.z = ylds[lm][w * 16 + lg * 4 + 2];
        am.w = ylds[lm][w * 16 + lg * 4 + 3];
        #pragma unroll
        for (int tg = 0; tg < 3; ++tg) {
            unsigned short* o = (tg == 0) ? hk16 : (tg == 1) ? hv16 : g16;
            #pragma unroll
            for (int q = 0; q < 2; ++q) {
                const int nt = 2 * w + q;
                f32x4 acc = f32x4{0.f, 0.f, 0.f, 0.f};
                acc = __builtin_amdgcn_mfma_f32_16x16x32_bf16(
                    as_bf(am), as_bf(pf[tg * 512 + nt * 64 + l]), acc, 0, 0, 0);
                #pragma unroll
                for (int r = 0; r < 4; ++r)
                    o[(size_t)(n0 + lg * 4 + r) * HD + nt * 16 + lm] =
                        (unsigned short)f2bf_u(acc[r]);
            }
        }
    }
}

// ---------------- CSR build ----------------
__global__ __launch_bounds__(256) void k_deg(
    const int* __restrict__ edge_index, int* __restrict__ deg)
{
    for (int e = blockIdx.x * blockDim.x + threadIdx.x; e < EE;
         e += gridDim.x * blockDim.x)
        atomicAdd(&deg[edge_index[e]], 1);
}

__global__ __launch_bounds__(SCAN_B) void k_scan_block(
    const int* __restrict__ deg, int* __restrict__ base, int* __restrict__ bsum)
{
    const int i = blockIdx.x * SCAN_B + threadIdx.x;
    const int v = (i < NN) ? deg[i] : 0;
    __shared__ int s[SCAN_B];
    s[threadIdx.x] = v;
    __syncthreads();
    for (int off = 1; off < SCAN_B; off <<= 1) {
        int t = (threadIdx.x >= off) ? s[threadIdx.x - off] : 0;
        __syncthreads();
        s[threadIdx.x] += t;
        __syncthreads();
    }
    if (i < NN) base[i] = s[threadIdx.x] - v;
    if (threadIdx.x == SCAN_B - 1) bsum[blockIdx.x] = s[SCAN_B - 1];
}

__global__ __launch_bounds__(SCAN_B) void k_scan_top(int* __restrict__ bsum)
{
    const int i = threadIdx.x;
    const int v = (i < NBLK) ? bsum[i] : 0;
    __shared__ int s[SCAN_B];
    s[i] = v;
    __syncthreads();
    for (int off = 1; off < SCAN_B; off <<= 1) {
        int t = (i >= off) ? s[i - off] : 0;
        __syncthreads();
        s[i] += t;
        __syncthreads();
    }
    if (i < NBLK) bsum[i] = s[i] - v;
}

__global__ __launch_bounds__(SCAN_B) void k_scan_add(
    int* __restrict__ base, const int* __restrict__ bsum, int* __restrict__ cursor)
{
    const int i = blockIdx.x * SCAN_B + threadIdx.x;
    if (i < NN) {
        const int b = base[i] + bsum[i >> 8];
        base[i] = b;
        cursor[i] = b;
    }
}

__global__ __launch_bounds__(256) void k_scatter(
    const int* __restrict__ edge_index, int* __restrict__ cursor,
    int* __restrict__ eidx, int* __restrict__ rowv, int* __restrict__ colv)
{
    for (int e = blockIdx.x * blockDim.x + threadIdx.x; e < EE;
         e += gridDim.x * blockDim.x) {
        const int r = edge_index[e];
        const int pos = atomicAdd(&cursor[r], 1);
        eidx[pos] = e;
        rowv[pos] = r;
        colv[pos] = edge_index[EE + e];
    }
}

// ---------------- edge-MLP weight fragment packer (1 block) ----------------
__global__ __launch_bounds__(256) void k_wfrag(
    const float* __restrict__ wk1_w, const float* __restrict__ wk2_w,
    const float* __restrict__ wv1_w, const float* __restrict__ wv2_w,
    uint4* __restrict__ frag)
{
    const int t = threadIdx.x;
    const int l = t & 63;
    const int lm = l & 15, lg = l >> 4;
    {
        const int f = t >> 6;          // 0..3
        const int kt = f >> 1, nt = f & 1;
        const int out = nt * 16 + lm;
        uint4 a, b;
        unsigned ra[4], rb[4];
        #pragma unroll
        for (int p = 0; p < 4; ++p) {
            const int in0 = kt * 32 + lg * 8 + 2 * p;
            ra[p] = pk2(wk1_w[(size_t)out * ECD + in0], wk1_w[(size_t)out * ECD + in0 + 1]);
            rb[p] = pk2(wv1_w[(size_t)out * ECD + in0], wv1_w[(size_t)out * ECD + in0 + 1]);
        }
        a.x = ra[0]; a.y = ra[1]; a.z = ra[2]; a.w = ra[3];
        b.x = rb[0]; b.y = rb[1]; b.z = rb[2]; b.w = rb[3];
        frag[f * 64 + l] = a;
        frag[(6 + f) * 64 + l] = b;
    }
    if (t < 128) {
        const int nt = t >> 6;
        const int out = nt * 16 + lm;
        uint4 a, b;
        unsigned ra[4], rb[4];
        #pragma unroll
        for (int p = 0; p < 4; ++p) {
            const int in0 = lg * 8 + 2 * p;
            ra[p] = pk2(wk2_w[(size_t)out * HH + in0], wk2_w[(size_t)out * HH + in0 + 1]);
            rb[p] = pk2(wv2_w[(size_t)out * HH + in0], wv2_w[(size_t)out * HH + in0 + 1]);
        }
        a.x = ra[0]; a.y = ra[1]; a.z = ra[2]; a.w = ra[3];
        b.x = rb[0]; b.y = rb[1]; b.z = rb[2]; b.w = rb[3];
        frag[(4 + nt) * 64 + l] = a;
        frag[(10 + nt) * 64 + l] = b;
    }
}

// ---------------- out_w fragment packer: owf[nt*4+kt][64] ----------------
__global__ __launch_bounds__(256) void k_owfrag(
    const float* __restrict__ out_w, uint4* __restrict__ owf)
{
    const int t = threadIdx.x;
    const int l = t & 63;
    const int lm = l & 15, lg = l >> 4;
    #pragma unroll
    for (int it = 0; it < 8; ++it) {
        const int f = (t >> 6) + it * 4;   // 0..31 = nt*4+kt
        const int nt = f >> 2, kt = f & 3;
        const int n = nt * 16 + lm;
        unsigned r[4];
        #pragma unroll
        for (int p = 0; p < 4; ++p) {
            const int k0 = kt * 32 + lg * 8 + 2 * p;
            r[p] = pk2(out_w[(size_t)n * HD + k0], out_w[(size_t)n * HD + k0 + 1]);
        }
        uint4 o; o.x = r[0]; o.y = r[1]; o.z = r[2]; o.w = r[3];
        owf[f * 64 + l] = o;
    }
}

// ---------------- K2: MFMA edge kernel (wave = 64 edges, direct f32 ea) -----
__global__ __launch_bounds__(256) void k_edge_mfma(
    const float* __restrict__ ea, const int* __restrict__ eidx,
    const int* __restrict__ rowv, const int* __restrict__ colv,
    const unsigned* __restrict__ hk_bf, const unsigned* __restrict__ g_bf,
    const float* __restrict__ c0_in, const uint4* __restrict__ frag,
    const float* __restrict__ wk1_b, const float* __restrict__ wk2_b,
    const float* __restrict__ wv1_b, const float* __restrict__ wv2_b,
    float* __restrict__ qkP, unsigned* __restrict__ wvP)
{
    __shared__ float lds[4][64 * LSTR];
    const int w = threadIdx.x >> 6, l = threadIdx.x & 63;
    const int lm = l & 15, lg = l >> 4;
    float* L = lds[w];
    const int e0 = blockIdx.x * 256 + w * 64;
    const int pos = e0 + l;
    const int row = rowv[pos];
    const int col = colv[pos];

    // A fragments: load original-order f32 ea via eidx, convert to bf16
    uint4 eaf[4][2];
    #pragma unroll
    for (int mt = 0; mt < 4; ++mt) {
        const int ee = eidx[e0 + mt * 16 + lm];
        const float* ep = ea + (size_t)ee * ECD + lg * 8;
        const float4 a0 = *(const float4*)(ep);
        const float4 a1 = *(const float4*)(ep + 4);
        const float4 b0 = *(const float4*)(ep + 32);
        const float4 b1 = *(const float4*)(ep + 36);
        eaf[mt][0].x = pk2f(a0.x, a0.y); eaf[mt][0].y = pk2f(a0.z, a0.w);
        eaf[mt][0].z = pk2f(a1.x, a1.y); eaf[mt][0].w = pk2f(a1.z, a1.w);
        eaf[mt][1].x = pk2f(b0.x, b0.y); eaf[mt][1].y = pk2f(b0.z, b0.w);
        eaf[mt][1].z = pk2f(b1.x, b1.y); eaf[mt][1].w = pk2f(b1.z, b1.w);
    }

    // ================= K path =================
    {
        const float b1a = wk1_b[lm], b1b = wk1_b[16 + lm];
        f32x4 acc[4][2];
        #pragma unroll
        for (int mt = 0; mt < 4; ++mt) {
            acc[mt][0] = f32x4{b1a, b1a, b1a, b1a};
            acc[mt][1] = f32x4{b1b, b1b, b1b, b1b};
        }
        const uint4 f00 = frag[0 * 64 + l], f01 = frag[1 * 64 + l];
        const uint4 f10 = frag[2 * 64 + l], f11 = frag[3 * 64 + l];
        #pragma unroll
        for (int mt = 0; mt < 4; ++mt) {
            acc[mt][0] = __builtin_amdgcn_mfma_f32_16x16x32_bf16(as_bf(eaf[mt][0]), as_bf(f00), acc[mt][0], 0, 0, 0);
            acc[mt][1] = __builtin_amdgcn_mfma_f32_16x16x32_bf16(as_bf(eaf[mt][0]), as_bf(f01), acc[mt][1], 0, 0, 0);
            acc[mt][0] = __builtin_amdgcn_mfma_f32_16x16x32_bf16(as_bf(eaf[mt][1]), as_bf(f10), acc[mt][0], 0, 0, 0);
            acc[mt][1] = __builtin_amdgcn_mfma_f32_16x16x32_bf16(as_bf(eaf[mt][1]), as_bf(f11), acc[mt][1], 0, 0, 0);
        }
        #pragma unroll
        for (int mt = 0; mt < 4; ++mt)
            #pragma unroll
            for (int nt = 0; nt < 2; ++nt)
                #pragma unroll
                for (int r = 0; r < 4; ++r)
                    L[(mt * 16 + lg * 4 + r) * LSTR + nt * 16 + lm] = ssp_f(acc[mt][nt][r]);

        const float b2a = wk2_b[lm], b2b = wk2_b[16 + lm];
        f32x4 acc2[4][2];
        const uint4 f20 = frag[4 * 64 + l], f21 = frag[5 * 64 + l];
        #pragma unroll
        for (int mt = 0; mt < 4; ++mt) {
            acc2[mt][0] = f32x4{b2a, b2a, b2a, b2a};
            acc2[mt][1] = f32x4{b2b, b2b, b2b, b2b};
            float av[8];
            #pragma unroll
            for (int j = 0; j < 8; ++j)
                av[j] = L[(mt * 16 + lm) * LSTR + lg * 8 + j];
            uint4 a2;
            a2.x = pk2f(av[0], av[1]); a2.y = pk2f(av[2], av[3]);
            a2.z = pk2f(av[4], av[5]); a2.w = pk2f(av[6], av[7]);
            acc2[mt][0] = __builtin_amdgcn_mfma_f32_16x16x32_bf16(as_bf(a2), as_bf(f20), acc2[mt][0], 0, 0, 0);
            acc2[mt][1] = __builtin_amdgcn_mfma_f32_16x16x32_bf16(as_bf(a2), as_bf(f21), acc2[mt][1], 0, 0, 0);
        }
        #pragma unroll
        for (int mt = 0; mt < 4; ++mt)
            #pragma unroll
            for (int nt = 0; nt < 2; ++nt)
                #pragma unroll
                for (int r = 0; r < 4; ++r)
                    L[(mt * 16 + lg * 4 + r) * LSTR + nt * 16 + lm] = acc2[mt][nt][r];
    }

    float wk[32];
    #pragma unroll
    for (int j = 0; j < 32; ++j) wk[j] = L[l * LSTR + j];

    {
        const uint4* hkp = (const uint4*)(hk_bf + (size_t)col * 64);
        const uint4* gp  = (const uint4*)(g_bf  + (size_t)row * 64);
        const float4 c0v = *(const float4*)(c0_in + (size_t)row * NHD);
        #pragma unroll
        for (int h = 0; h < NHD; ++h) {
            float s = 0.f;
            #pragma unroll
            for (int q = 0; q < 4; ++q) {
                const uint4 ku = hkp[h * 4 + q];
                const uint4 gu = gp[h * 4 + q];
                float ka, kb, ga, gb;
                unp2(ku.x, ka, kb); unp2(gu.x, ga, gb);
                s = fmaf(wk[q * 8 + 0] * ka, ga, s);
                s = fmaf(wk[q * 8 + 1] * kb, gb, s);
                unp2(ku.y, ka, kb); unp2(gu.y, ga, gb);
                s = fmaf(wk[q * 8 + 2] * ka, ga, s);
                s = fmaf(wk[q * 8 + 3] * kb, gb, s);
                unp2(ku.z, ka, kb); unp2(gu.z, ga, gb);
                s = fmaf(wk[q * 8 + 4] * ka, ga, s);
                s = fmaf(wk[q * 8 + 5] * kb, gb, s);
                unp2(ku.w, ka, kb); unp2(gu.w, ga, gb);
                s = fmaf(wk[q * 8 + 6] * ka, ga, s);
                s = fmaf(wk[q * 8 + 7] * kb, gb, s);
            }
            const float c0h = (h == 0) ? c0v.x : (h == 1) ? c0v.y : (h == 2) ? c0v.z : c0v.w;
            qkP[(size_t)h * EE + pos] = s + c0h;
        }
    }

    // ================= V path =================
    {
        const float b1a = wv1_b[lm], b1b = wv1_b[16 + lm];
        f32x4 acc[4][2];
        #pragma unroll
        for (int mt = 0; mt < 4; ++mt) {
            acc[mt][0] = f32x4{b1a, b1a, b1a, b1a};
            acc[mt][1] = f32x4{b1b, b1b, b1b, b1b};
        }
        const uint4 f00 = frag[6 * 64 + l], f01 = frag[7 * 64 + l];
        const uint4 f10 = frag[8 * 64 + l], f11 = frag[9 * 64 + l];
        #pragma unroll
        for (int mt = 0; mt < 4; ++mt) {
            acc[mt][0] = __builtin_amdgcn_mfma_f32_16x16x32_bf16(as_bf(eaf[mt][0]), as_bf(f00), acc[mt][0], 0, 0, 0);
            acc[mt][1] = __builtin_amdgcn_mfma_f32_16x16x32_bf16(as_bf(eaf[mt][0]), as_bf(f01), acc[mt][1], 0, 0, 0);
            acc[mt][0] = __builtin_amdgcn_mfma_f32_16x16x32_bf16(as_bf(eaf[mt][1]), as_bf(f10), acc[mt][0], 0, 0, 0);
            acc[mt][1] = __builtin_amdgcn_mfma_f32_16x16x32_bf16(as_bf(eaf[mt][1]), as_bf(f11), acc[mt][1], 0, 0, 0);
        }
        #pragma unroll
        for (int mt = 0; mt < 4; ++mt)
            #pragma unroll
            for (int nt = 0; nt < 2; ++nt)
                #pragma unroll
                for (int r = 0; r < 4; ++r)
                    L[(mt * 16 + lg * 4 + r) * LSTR + nt * 16 + lm] = ssp_f(acc[mt][nt][r]);

        const float b2a = wv2_b[lm], b2b = wv2_b[16 + lm];
        f32x4 acc2[4][2];
        const uint4 f20 = frag[10 * 64 + l], f21 = frag[11 * 64 + l];
        #pragma unroll
        for (int mt = 0; mt < 4; ++mt) {
            acc2[mt][0] = f32x4{b2a, b2a, b2a, b2a};
            acc2[mt][1] = f32x4{b2b, b2b, b2b, b2b};
            float av[8];
            #pragma unroll
            for (int j = 0; j < 8; ++j)
                av[j] = L[(mt * 16 + lm) * LSTR + lg * 8 + j];
            uint4 a2;
            a2.x = pk2f(av[0], av[1]); a2.y = pk2f(av[2], av[3]);
            a2.z = pk2f(av[4], av[5]); a2.w = pk2f(av[6], av[7]);
            acc2[mt][0] = __builtin_amdgcn_mfma_f32_16x16x32_bf16(as_bf(a2), as_bf(f20), acc2[mt][0], 0, 0, 0);
            acc2[mt][1] = __builtin_amdgcn_mfma_f32_16x16x32_bf16(as_bf(a2), as_bf(f21), acc2[mt][1], 0, 0, 0);
        }
        #pragma unroll
        for (int mt = 0; mt < 4; ++mt)
            #pragma unroll
            for (int nt = 0; nt < 2; ++nt)
                #pragma unroll
                for (int r = 0; r < 4; ++r)
                    L[(mt * 16 + lg * 4 + r) * LSTR + nt * 16 + lm] = acc2[mt][nt][r];
    }

    #pragma unroll
    for (int k = 0; k < 16; ++k) {
        const int f = k * 64 + l;
        const int pr = f >> 4, i = f & 15;
        wvP[(size_t)e0 * 16 + f] = pk2f(L[pr * LSTR + 2 * i], L[pr * LSTR + 2 * i + 1]);
    }
}

// ---------------- K3: fused aggregation + wvl matvec + LN2 + ssp ------------
__global__ __launch_bounds__(256) void k_aggr_tail(
    const float* __restrict__ qkP, const unsigned* __restrict__ wvP,
    const unsigned* __restrict__ hv_bf, const int* __restrict__ colv,
    const int* __restrict__ base, const int* __restrict__ deg,
    const float* __restrict__ x,
    const float* __restrict__ wvl_w, const float* __restrict__ wvl_b,
    const float* __restrict__ ln2_g, const float* __restrict__ ln2_b,
    float* __restrict__ x2P, unsigned* __restrict__ sbf)
{
    __shared__ float swvl[HH * 34];
    __shared__ float su[4][HD];
    for (int idx = threadIdx.x; idx < HH * HH; idx += 256)
        swvl[(idx >> 5) * 34 + (idx & 31)] = wvl_w[idx];
    __syncthreads();

    const int w = threadIdx.x >> 6, l = threadIdx.x & 63;
    const int h = l >> 4, i = l & 15;
    const int t0 = 2 * l;
    const float2 lg2 = *(const float2*)(ln2_g + t0);
    const float2 lb2 = *(const float2*)(ln2_b + t0);
    const int j0 = 2 * i;
    const float2 wb2 = *(const float2*)(wvl_b + j0);
    float* sb = su[w];

    for (int n = blockIdx.x * 4 + w; n < NN; n += 2048 * 4) {
        const int b0 = base[n];
        const int dn = deg[n];
        const float2 xv = *(const float2*)(x + (size_t)n * HD + t0);

        float acc0 = 0.f, acc1 = 0.f;
        if (dn > 0) {
            const float* qkh = qkP + (size_t)h * EE + b0;
            const int emax = b0 + dn - 1;
            float m = -3.0e38f;
            for (int c = i; c < dn; c += 16) m = fmaxf(m, qkh[c]);
            #pragma unroll
            for (int off = 1; off < 16; off <<= 1)
                m = fmaxf(m, __shfl_xor(m, off));
            float den = 0.f;
            for (int c = i; c < dn; c += 16) den += __expf(qkh[c] - m);
            #pragma unroll
            for (int off = 1; off < 16; off <<= 1) den += __shfl_xor(den, off);
            const float rden = (den > 0.f) ? 1.0f / den : 0.f;
            for (int c0 = 0; c0 < dn; c0 += 16) {
                const int tn = (dn - c0 < 16) ? (dn - c0) : 16;
                float ex = 0.f; int cq = 0;
                if (i < tn) {
                    ex = __expf(qkh[c0 + i] - m) * rden;
                    cq = colv[b0 + c0 + i];
                }
                const int t4 = (tn + 3) & ~3;
                for (int i2 = 0; i2 < t4; i2 += 4) {
                    #pragma unroll
                    for (int u = 0; u < 4; ++u) {
                        const int src = (l & 48) | (i2 + u);
                        const float wgt = __shfl(ex, src);
                        const int ce = __shfl(cq, src);
                        int ep = b0 + c0 + i2 + u;
                        ep = (ep > emax) ? emax : ep;
                        const unsigned hvv = hv_bf[(size_t)ce * 64 + l];
                        const unsigned wvv = wvP[(size_t)ep * 16 + i];
                        float ha, hb, wa, wb;
                        unp2(hvv, ha, hb); unp2(wvv, wa, wb);
                        acc0 = fmaf(wgt, wa * ha, acc0);
                        acc1 = fmaf(wgt, wb * hb, acc1);
                    }
                }
            }
        }

        *(float2*)(sb + t0) = make_float2(acc0, acc1);

        float ag0 = 0.f, ag1 = 0.f;
        if (dn > 0) {
            ag0 = wb2.x; ag1 = wb2.y;
            const float* uh = sb + h * HH;
            const float* r0 = swvl + j0 * 34;
            const float* r1 = r0 + 34;
            #pragma unroll
            for (int q = 0; q < 16; ++q) {
                const float2 u  = *(const float2*)(uh + 2 * q);
                const float2 a  = *(const float2*)(r0 + 2 * q);
                const float2 bb = *(const float2*)(r1 + 2 * q);
                ag0 = fmaf(u.x, a.x, ag0);  ag0 = fmaf(u.y, a.y, ag0);
                ag1 = fmaf(u.x, bb.x, ag1); ag1 = fmaf(u.y, bb.y, ag1);
            }
        }
        const float x20 = ag0 + xv.x;
        const float x21 = ag1 + xv.y;

        float s1 = x20 + x21, s2 = x20 * x20 + x21 * x21;
        #pragma unroll
        for (int off = 1; off < 64; off <<= 1) {
            s1 += __shfl_xor(s1, off);
            s2 += __shfl_xor(s2, off);
        }
        const float mean = s1 * (1.0f / HD);
        const float var  = s2 * (1.0f / HD) - mean * mean;
        const float rstd = rsqrtf(var + 1e-5f);
        const float ss0 = ssp_f((x20 - mean) * rstd * lg2.x + lb2.x);
        const float ss1 = ssp_f((x21 - mean) * rstd * lg2.y + lb2.y);

        *(float2*)(x2P + (size_t)n * HD + t0) = make_float2(x20, x21);
        sbf[(size_t)n * 64 + l] = pk2(ss0, ss1);
    }
}

// ---------------- K3c: MFMA out-GEMM: out = sbf @ out_w^T + out_b + x2 ------
__global__ __launch_bounds__(256) void k_tail_gemm(
    const unsigned short* __restrict__ sbf, const float* __restrict__ x2P,
    const uint4* __restrict__ owf, const float* __restrict__ out_b,
    float* __restrict__ out)
{
    const int w = threadIdx.x >> 6, l = threadIdx.x & 63;
    const int lm = l & 15, lg = l >> 4;
    const int tile = blockIdx.x * 4 + w;
    if (tile * 16 >= NN) return;
    const int n0 = tile * 16;

    uint4 af[4];
    #pragma unroll
    for (int kt = 0; kt < 4; ++kt)
        af[kt] = *(const uint4*)(sbf + (size_t)(n0 + lm) * HD + kt * 32 + lg * 8);

    f32x4 acc[8];
    #pragma unroll
    for (int nt = 0; nt < 8; ++nt) {
        const float b = out_b[nt * 16 + lm];
        acc[nt] = f32x4{b, b, b, b};
    }
    #pragma unroll
    for (int kt = 0; kt < 4; ++kt) {
        #pragma unroll
        for (int nt = 0; nt < 8; ++nt)
            acc[nt] = __builtin_amdgcn_mfma_f32_16x16x32_bf16(
                as_bf(af[kt]), as_bf(owf[(nt * 4 + kt) * 64 + l]), acc[nt], 0, 0, 0);
    }
    #pragma unroll
    for (int nt = 0; nt < 8; ++nt)
        #pragma unroll
        for (int r = 0; r < 4; ++r) {
            const size_t idx = (size_t)(n0 + lg * 4 + r) * HD + nt * 16 + lm;
            out[idx] = acc[nt][r] + x2P[idx];
        }
}

extern "C" void kernel_launch(void* const* d_in, const int* in_sizes, int n_in,
                              void* d_out, int out_size, void* d_ws, size_t ws_size,
                              hipStream_t stream) {
    const float* x         = (const float*)d_in[0];
    const float* edge_attr = (const float*)d_in[1];
    const int*   edge_index= (const int*)  d_in[2];
    const float* k_w   = (const float*)d_in[3];
    const float* q_w   = (const float*)d_in[4];
    const float* v_w   = (const float*)d_in[5];
    const float* wk1_w = (const float*)d_in[6];
    const float* wk1_b = (const float*)d_in[7];
    const float* wk2_w = (const float*)d_in[8];
    const float* wk2_b = (const float*)d_in[9];
    const float* wkl_w = (const float*)d_in[10];
    const float* wkl_b = (const float*)d_in[11];
    const float* wv1_w = (const float*)d_in[12];
    const float* wv1_b = (const float*)d_in[13];
    const float* wv2_w = (const float*)d_in[14];
    const float* wv2_b = (const float*)d_in[15];
    const float* wvl_w = (const float*)d_in[16];
    const float* wvl_b = (const float*)d_in[17];
    const float* out_w = (const float*)d_in[18];
    const float* out_b = (const float*)d_in[19];
    const float* ln1_g = (const float*)d_in[20];
    const float* ln1_b = (const float*)d_in[21];
    const float* ln2_g = (const float*)d_in[22];
    const float* ln2_b = (const float*)d_in[23];

    char* ws = (char*)d_ws;
    unsigned* hk_bf = (unsigned*)ws;            ws += (size_t)NN * 64 * 4;
    unsigned* hv_bf = (unsigned*)ws;            ws += (size_t)NN * 64 * 4;
    unsigned* g_bf  = (unsigned*)ws;            ws += (size_t)NN * 64 * 4;
    float* c0  = (float*)ws;                    ws += (size_t)NN * NHD * 4;
    float* qkP = (float*)ws;                    ws += (size_t)NHD * EE * 4;
    unsigned* wvP = (unsigned*)ws;              ws += (size_t)EE * 16 * 4;
    uint4* fragbuf = (uint4*)ws;                ws += (size_t)12 * 64 * 16;
    uint4* owfbuf  = (uint4*)ws;                ws += (size_t)32 * 64 * 16;
    uint4* pfbuf   = (uint4*)ws;                ws += (size_t)3 * 512 * 16;
    float* cw      = (float*)ws;                ws += (size_t)512 * 4;
    float* x2P = (float*)ws;                    ws += (size_t)NN * HD * 4;
    unsigned* sbf = (unsigned*)ws;              ws += (size_t)NN * 64 * 4;
    int* deg    = (int*)ws;                     ws += (size_t)NN * 4;
    int* base   = (int*)ws;                     ws += (size_t)NN * 4;
    int* cursor = (int*)ws;                     ws += (size_t)NN * 4;
    int* bsum   = (int*)ws;                     ws += (size_t)SCAN_B * 4;
    int* eidx   = (int*)ws;                     ws += (size_t)EE * 4;
    int* rowv   = (int*)ws;                     ws += (size_t)EE * 4;
    int* colv   = (int*)ws;                     ws += (size_t)EE * 4;

    (void)hipMemsetAsync(deg, 0, (size_t)NN * 4, stream);

    k_wfrag<<<1, 256, 0, stream>>>(wk1_w, wk2_w, wv1_w, wv2_w, fragbuf);
    k_owfrag<<<1, 256, 0, stream>>>(out_w, owfbuf);
    k_pwfrag<<<1, 256, 0, stream>>>(k_w, v_w, q_w, wkl_w, wkl_b, pfbuf, cw);
    k_ln1proj<<<1024, 256, 0, stream>>>(x, ln1_g, ln1_b, cw, pfbuf, c0,
        (unsigned short*)hk_bf, (unsigned short*)hv_bf, (unsigned short*)g_bf);
    k_deg<<<1024, 256, 0, stream>>>(edge_index, deg);
    k_scan_block<<<NBLK, SCAN_B, 0, stream>>>(deg, base, bsum);
    k_scan_top<<<1, SCAN_B, 0, stream>>>(bsum);
    k_scan_add<<<NBLK, SCAN_B, 0, stream>>>(base, bsum, cursor);
    k_scatter<<<1024, 256, 0, stream>>>(edge_index, cursor, eidx, rowv, colv);
    k_edge_mfma<<<EE / 256, 256, 0, stream>>>(edge_attr, eidx, rowv, colv,
        hk_bf, g_bf, c0, fragbuf,
        wk1_b, wk2_b, wv1_b, wv2_b, qkP, wvP);
    k_aggr_tail<<<2048, 256, 0, stream>>>(qkP, wvP, hv_bf, colv, base, deg,
        x, wvl_w, wvl_b, ln2_g, ln2_b, x2P, sbf);
    k_tail_gemm<<<(NN / 16 + 3) / 4, 256, 0, stream>>>(
        (const unsigned short*)sbf, x2P, owfbuf, out_b, (float*)d_out);
}